// Round 1
// baseline (6222.426 us; speedup 1.0000x reference)
//
#include <hip/hip_runtime.h>

#define NN 100000
#define NE 1600000
#define DF 128
#define NH (NN * DF)
#define EPS 1e-5f

__device__ __forceinline__ void atomAddF(float* p, float v) {
#if defined(__gfx90a__) || defined(__gfx942__) || defined(__gfx950__)
    unsafeAtomicAdd(p, v);
#else
    atomicAdd(p, v);
#endif
}

// ---- degree ----
__global__ void k_count(const int* __restrict__ dst, float* __restrict__ deg) {
    int e = blockIdx.x * blockDim.x + threadIdx.x;
    if (e < NE) atomAddF(&deg[dst[e]], 1.0f);
}

__global__ void k_deg(const float* __restrict__ deg, float* __restrict__ dis,
                      float* __restrict__ di) {
    int i = blockIdx.x * blockDim.x + threadIdx.x;
    if (i < NN) {
        float d = deg[i] + 1.0f;
        dis[i] = rsqrtf(d);
        di[i] = 1.0f / d;
    }
}

// ---- dense matmul: Y[r][c] = sum_k X[r][k] * W[k][c], K=128, 128 cols ----
// block: 256 threads covers 64 rows x 128 cols; thread tile 8 rows x 4 cols.
__launch_bounds__(256, 2)
__global__ void k_mm128(const float* __restrict__ X, const float* __restrict__ Wg,
                        float* __restrict__ Y, int nrows) {
    __shared__ float ws[128 * 128];
    const float4* Wg4 = (const float4*)Wg;
    float4* ws4 = (float4*)ws;
#pragma unroll
    for (int i = 0; i < 16; ++i) ws4[threadIdx.x + i * 256] = Wg4[threadIdx.x + i * 256];
    __syncthreads();

    const int ty = threadIdx.x >> 5;   // 0..7
    const int tx = threadIdx.x & 31;   // 0..31
    const int row0 = blockIdx.x * 64 + ty * 8;
    const int col = tx * 4;

    float acc[8][4];
#pragma unroll
    for (int i = 0; i < 8; ++i)
#pragma unroll
        for (int j = 0; j < 4; ++j) acc[i][j] = 0.0f;

    for (int k4 = 0; k4 < 128; k4 += 4) {
        float4 xv[8];
#pragma unroll
        for (int i = 0; i < 8; ++i) {
            int r = row0 + i;
            xv[i] = (r < nrows) ? *(const float4*)&X[r * 128 + k4]
                                : make_float4(0.f, 0.f, 0.f, 0.f);
        }
#pragma unroll
        for (int kk = 0; kk < 4; ++kk) {
            float4 w4 = *(const float4*)&ws[(k4 + kk) * 128 + col];
#pragma unroll
            for (int i = 0; i < 8; ++i) {
                float xs = (kk == 0) ? xv[i].x : (kk == 1) ? xv[i].y : (kk == 2) ? xv[i].z : xv[i].w;
                acc[i][0] += xs * w4.x;
                acc[i][1] += xs * w4.y;
                acc[i][2] += xs * w4.z;
                acc[i][3] += xs * w4.w;
            }
        }
    }
#pragma unroll
    for (int i = 0; i < 8; ++i) {
        int r = row0 + i;
        if (r < nrows)
            *(float4*)&Y[r * 128 + col] = make_float4(acc[i][0], acc[i][1], acc[i][2], acc[i][3]);
    }
}

// ---- init agg with self-loop + bias: AGG[r][c] = HW[r][c]*di[r] + b[c] ----
__global__ void k_pre(const float* __restrict__ HW, const float* __restrict__ di,
                      const float* __restrict__ b, float* __restrict__ AGG, int nrows) {
    int t = blockIdx.x * blockDim.x + threadIdx.x;
    if (t >= nrows * 32) return;
    int row = t >> 5;
    int c4 = (t & 31) * 4;
    float dv = di[row];
    float4 h = *(const float4*)&HW[row * 128 + c4];
    float4 bb = *(const float4*)&b[c4];
    float4 o;
    o.x = h.x * dv + bb.x;
    o.y = h.y * dv + bb.y;
    o.z = h.z * dv + bb.z;
    o.w = h.w * dv + bb.w;
    *(float4*)&AGG[row * 128 + c4] = o;
}

// ---- edge scatter: AGG[dst] += H[src] * dis[src]*dis[dst]; 32 lanes/edge ----
__global__ void k_scatter128(const float* __restrict__ Hm, const int* __restrict__ src,
                             const int* __restrict__ dst, const float* __restrict__ dis,
                             float* __restrict__ agg) {
    long long gid = (long long)blockIdx.x * blockDim.x + threadIdx.x;
    int e = (int)(gid >> 5);
    int q = ((int)gid & 31) * 4;
    if (e >= NE) return;
    int s = src[e], d = dst[e];
    float coef = dis[s] * dis[d];
    float4 v = *(const float4*)&Hm[s * 128 + q];
    float* ap = &agg[d * 128 + q];
    atomAddF(ap + 0, v.x * coef);
    atomAddF(ap + 1, v.y * coef);
    atomAddF(ap + 2, v.z * coef);
    atomAddF(ap + 3, v.w * coef);
}

// ---- column stats: stats[c] = sum, stats[128+c] = sumsq ----
__global__ void k_stats(const float* __restrict__ V, float* __restrict__ stats, int nrows) {
    int c = threadIdx.x & 127;
    int half = threadIdx.x >> 7;  // 0..1
    float s = 0.f, s2 = 0.f;
#pragma unroll 4
    for (int i = 0; i < 32; ++i) {
        int r = blockIdx.x * 64 + half + 2 * i;
        if (r < nrows) {
            float v = V[r * 128 + c];
            s += v;
            s2 += v * v;
        }
    }
    __shared__ float ls[256], ls2[256];
    ls[threadIdx.x] = s;
    ls2[threadIdx.x] = s2;
    __syncthreads();
    if (half == 0) {
        atomAddF(&stats[c], ls[c] + ls[c + 128]);
        atomAddF(&stats[128 + c], ls2[c] + ls2[c + 128]);
    }
}

// ---- BN params: par[c] = scale, par[128+c] = shift ----
__global__ void k_bnparams(const float* __restrict__ stats, const float* __restrict__ g,
                           const float* __restrict__ be, float* __restrict__ par) {
    int c = threadIdx.x;
    float mu = stats[c] * (1.0f / NN);
    float var = stats[128 + c] * (1.0f / NN) - mu * mu;
    float inv = rsqrtf(var + EPS);
    float sc = inv * g[c];
    par[c] = sc;
    par[128 + c] = be[c] - mu * sc;
}

// ---- normalize + relu ----
__global__ void k_norm(const float* __restrict__ V, const float* __restrict__ par,
                       float* __restrict__ O, int nrows) {
    int t = blockIdx.x * blockDim.x + threadIdx.x;
    if (t >= nrows * 32) return;
    int row = t >> 5;
    int c4 = (t & 31) * 4;
    float4 v = *(const float4*)&V[row * 128 + c4];
    float4 sc = *(const float4*)&par[c4];
    float4 sh = *(const float4*)&par[128 + c4];
    float4 o;
    o.x = fmaxf(v.x * sc.x + sh.x, 0.f);
    o.y = fmaxf(v.y * sc.y + sh.y, 0.f);
    o.z = fmaxf(v.z * sc.z + sh.z, 0.f);
    o.w = fmaxf(v.w * sc.w + sh.w, 0.f);
    *(float4*)&O[row * 128 + c4] = o;
}

// ---- layer-3 matmul: Z[n][0..1] = X[n] @ W3 (128x2); one wave per node ----
__global__ void k_mm2(const float* __restrict__ X, const float* __restrict__ W3,
                      float* __restrict__ Z) {
    int wid = (int)(((long long)blockIdx.x * blockDim.x + threadIdx.x) >> 6);
    int lane = threadIdx.x & 63;
    if (wid >= NN) return;
    float2 x2 = *(const float2*)&X[wid * 128 + lane * 2];
    float4 w4 = *(const float4*)&W3[lane * 4];  // rows 2l,2l+1 of [128][2]
    float p0 = x2.x * w4.x + x2.y * w4.z;
    float p1 = x2.x * w4.y + x2.y * w4.w;
#pragma unroll
    for (int off = 32; off; off >>= 1) {
        p0 += __shfl_xor(p0, off);
        p1 += __shfl_xor(p1, off);
    }
    if (lane == 0) *(float2*)&Z[wid * 2] = make_float2(p0, p1);
}

__global__ void k_pre3(const float* __restrict__ Z, const float* __restrict__ di,
                       const float* __restrict__ b3, float* __restrict__ A3) {
    int n = blockIdx.x * blockDim.x + threadIdx.x;
    if (n >= NN) return;
    float dv = di[n];
    float2 z = *(const float2*)&Z[n * 2];
    *(float2*)&A3[n * 2] = make_float2(z.x * dv + b3[0], z.y * dv + b3[1]);
}

__global__ void k_scatter2(const float* __restrict__ Z, const int* __restrict__ src,
                           const int* __restrict__ dst, const float* __restrict__ dis,
                           float* __restrict__ A3) {
    int e = blockIdx.x * blockDim.x + threadIdx.x;
    if (e >= NE) return;
    int s = src[e], d = dst[e];
    float coef = dis[s] * dis[d];
    float2 z = *(const float2*)&Z[s * 2];
    atomAddF(&A3[d * 2 + 0], z.x * coef);
    atomAddF(&A3[d * 2 + 1], z.y * coef);
}

__global__ void k_soft(const float* __restrict__ A3, float* __restrict__ out) {
    int n = blockIdx.x * blockDim.x + threadIdx.x;
    if (n >= NN) return;
    float2 a = *(const float2*)&A3[n * 2];
    float m = fmaxf(a.x, a.y);
    float e0 = __expf(a.x - m), e1 = __expf(a.y - m);
    float s = 1.0f / (e0 + e1);
    *(float2*)&out[n * 2] = make_float2(e0 * s, e1 * s);
}

extern "C" void kernel_launch(void* const* d_in, const int* in_sizes, int n_in,
                              void* d_out, int out_size, void* d_ws, size_t ws_size,
                              hipStream_t stream) {
    const float* x  = (const float*)d_in[0];
    const float* W1 = (const float*)d_in[1];
    const float* b1 = (const float*)d_in[2];
    const float* g1 = (const float*)d_in[3];
    const float* be1= (const float*)d_in[4];
    const float* W2 = (const float*)d_in[5];
    const float* b2 = (const float*)d_in[6];
    const float* g2 = (const float*)d_in[7];
    const float* be2= (const float*)d_in[8];
    const float* W3 = (const float*)d_in[9];
    const float* b3 = (const float*)d_in[10];
    const int*   ei = (const int*)d_in[11];
    const int* srcp = ei;
    const int* dstp = ei + NE;
    float* out = (float*)d_out;

    float* B0   = (float*)d_ws;          // N x 128
    float* B1   = B0 + NH;               // N x 128
    float* B2   = B1 + NH;               // N x 128
    float* Z    = B2 + NH;               // N x 2
    float* A3   = Z + 2 * NN;            // N x 2
    float* deg  = A3 + 2 * NN;           // N
    float* dis  = deg + NN;              // N
    float* di   = dis + NN;              // N
    float* stats= di + NN;               // 256
    float* par  = stats + 256;           // 256

    const int B = 256;
    // degree
    hipMemsetAsync(deg, 0, NN * sizeof(float), stream);
    k_count<<<(NE + B - 1) / B, B, 0, stream>>>(dstp, deg);
    k_deg<<<(NN + B - 1) / B, B, 0, stream>>>(deg, dis, di);

    const int gMM  = (NN + 63) / 64;          // 1563
    const int gV4  = (NN * 32 + B - 1) / B;   // 12500
    const int gSC  = (int)(((long long)NE * 32 + B - 1) / B);  // 200000
    const int gN   = (NN + B - 1) / B;        // 391

    // ---- layer 1 ----
    k_mm128<<<gMM, B, 0, stream>>>(x, W1, B1, NN);
    k_pre<<<gV4, B, 0, stream>>>(B1, di, b1, B2, NN);
    k_scatter128<<<gSC, B, 0, stream>>>(B1, srcp, dstp, dis, B2);
    hipMemsetAsync(stats, 0, 256 * sizeof(float), stream);
    k_stats<<<gMM, B, 0, stream>>>(B2, stats, NN);
    k_bnparams<<<1, 128, 0, stream>>>(stats, g1, be1, par);
    k_norm<<<gV4, B, 0, stream>>>(B2, par, B0, NN);

    // ---- layer 2 ----
    k_mm128<<<gMM, B, 0, stream>>>(B0, W2, B1, NN);
    k_pre<<<gV4, B, 0, stream>>>(B1, di, b2, B2, NN);
    k_scatter128<<<gSC, B, 0, stream>>>(B1, srcp, dstp, dis, B2);
    hipMemsetAsync(stats, 0, 256 * sizeof(float), stream);
    k_stats<<<gMM, B, 0, stream>>>(B2, stats, NN);
    k_bnparams<<<1, 128, 0, stream>>>(stats, g2, be2, par);
    k_norm<<<gV4, B, 0, stream>>>(B2, par, B0, NN);

    // ---- layer 3 + softmax ----
    k_mm2<<<(int)(((long long)NN * 64 + B - 1) / B), B, 0, stream>>>(B0, W3, Z);
    k_pre3<<<gN, B, 0, stream>>>(Z, di, b3, A3);
    k_scatter2<<<(NE + B - 1) / B, B, 0, stream>>>(Z, srcp, dstp, dis, A3);
    k_soft<<<gN, B, 0, stream>>>(A3, out);
}

// Round 2
// 1043.401 us; speedup vs baseline: 5.9636x; 5.9636x over previous
//
#include <hip/hip_runtime.h>

#define NN 100000
#define NE 1600000
#define DF 128
#define NH (NN * DF)
#define EPS 1e-5f
#define SCAN_NB 98   // ceil(NN/1024)

__device__ __forceinline__ void atomAddF(float* p, float v) {
#if defined(__gfx90a__) || defined(__gfx942__) || defined(__gfx950__)
    unsafeAtomicAdd(p, v);
#else
    atomicAdd(p, v);
#endif
}

// ---- integer degree count ----
__global__ void k_count(const int* __restrict__ dst, int* __restrict__ degi) {
    int e = blockIdx.x * blockDim.x + threadIdx.x;
    if (e < NE) atomicAdd(&degi[dst[e]], 1);
}

__global__ void k_deg(const int* __restrict__ degi, float* __restrict__ dis,
                      float* __restrict__ di) {
    int i = blockIdx.x * blockDim.x + threadIdx.x;
    if (i < NN) {
        float d = (float)degi[i] + 1.0f;
        dis[i] = rsqrtf(d);
        di[i] = 1.0f / d;
    }
}

// ---- prefix scan (exclusive) of degi -> row_ptr; 1024 elems/block ----
__global__ void k_scan1(const int* __restrict__ in, int* __restrict__ out,
                        int* __restrict__ bsum) {
    __shared__ int sh[256];
    int base = blockIdx.x * 1024;
    int t = threadIdx.x;
    int v[4];
    int s = 0;
#pragma unroll
    for (int i = 0; i < 4; ++i) {
        int idx = base + t * 4 + i;
        v[i] = (idx < NN) ? in[idx] : 0;
        s += v[i];
    }
    sh[t] = s;
    __syncthreads();
    for (int off = 1; off < 256; off <<= 1) {
        int x = (t >= off) ? sh[t - off] : 0;
        __syncthreads();
        sh[t] += x;
        __syncthreads();
    }
    int excl = sh[t] - s;
    if (t == 255) bsum[blockIdx.x] = sh[255];
    int run = excl;
#pragma unroll
    for (int i = 0; i < 4; ++i) {
        int idx = base + t * 4 + i;
        if (idx < NN) out[idx] = run;
        run += v[i];
    }
}

__global__ void k_scan2(int* __restrict__ bsum) {
    __shared__ int sh[128];
    int t = threadIdx.x;
    int v = (t < SCAN_NB) ? bsum[t] : 0;
    sh[t] = v;
    __syncthreads();
    for (int off = 1; off < 128; off <<= 1) {
        int x = (t >= off) ? sh[t - off] : 0;
        __syncthreads();
        sh[t] += x;
        __syncthreads();
    }
    if (t < SCAN_NB) bsum[t] = sh[t] - v;  // exclusive
}

__global__ void k_scan3(int* __restrict__ rp, const int* __restrict__ bsum,
                        int* __restrict__ cursor) {
    int base = blockIdx.x * 1024;
    int add = bsum[blockIdx.x];
#pragma unroll
    for (int i = 0; i < 4; ++i) {
        int idx = base + threadIdx.x + i * 256;
        if (idx < NN) {
            int v = rp[idx] + add;
            rp[idx] = v;
            cursor[idx] = v;
        }
    }
    if (blockIdx.x == 0 && threadIdx.x == 0) rp[NN] = NE;
}

// ---- place edges into CSR-by-dst; precompute per-edge coef ----
__global__ void k_place(const int* __restrict__ src, const int* __restrict__ dst,
                        const float* __restrict__ dis, int* __restrict__ cursor,
                        int* __restrict__ es, float* __restrict__ cf) {
    int e = blockIdx.x * blockDim.x + threadIdx.x;
    if (e >= NE) return;
    int s = src[e], d = dst[e];
    int p = atomicAdd(&cursor[d], 1);
    es[p] = s;
    cf[p] = dis[s] * dis[d];
}

// ---- dense matmul: Y[r][c] = sum_k X[r][k] * W[k][c], K=128, 128 cols ----
__launch_bounds__(256, 2)
__global__ void k_mm128(const float* __restrict__ X, const float* __restrict__ Wg,
                        float* __restrict__ Y, int nrows) {
    __shared__ float ws[128 * 128];
    const float4* Wg4 = (const float4*)Wg;
    float4* ws4 = (float4*)ws;
#pragma unroll
    for (int i = 0; i < 16; ++i) ws4[threadIdx.x + i * 256] = Wg4[threadIdx.x + i * 256];
    __syncthreads();

    const int ty = threadIdx.x >> 5;
    const int tx = threadIdx.x & 31;
    const int row0 = blockIdx.x * 64 + ty * 8;
    const int col = tx * 4;

    float acc[8][4];
#pragma unroll
    for (int i = 0; i < 8; ++i)
#pragma unroll
        for (int j = 0; j < 4; ++j) acc[i][j] = 0.0f;

    for (int k4 = 0; k4 < 128; k4 += 4) {
        float4 xv[8];
#pragma unroll
        for (int i = 0; i < 8; ++i) {
            int r = row0 + i;
            xv[i] = (r < nrows) ? *(const float4*)&X[r * 128 + k4]
                                : make_float4(0.f, 0.f, 0.f, 0.f);
        }
#pragma unroll
        for (int kk = 0; kk < 4; ++kk) {
            float4 w4 = *(const float4*)&ws[(k4 + kk) * 128 + col];
#pragma unroll
            for (int i = 0; i < 8; ++i) {
                float xs = (kk == 0) ? xv[i].x : (kk == 1) ? xv[i].y : (kk == 2) ? xv[i].z : xv[i].w;
                acc[i][0] += xs * w4.x;
                acc[i][1] += xs * w4.y;
                acc[i][2] += xs * w4.z;
                acc[i][3] += xs * w4.w;
            }
        }
    }
#pragma unroll
    for (int i = 0; i < 8; ++i) {
        int r = row0 + i;
        if (r < nrows)
            *(float4*)&Y[r * 128 + col] = make_float4(acc[i][0], acc[i][1], acc[i][2], acc[i][3]);
    }
}

// ---- CSR gather aggregation: one wave per dst node, fuses self-loop+bias ----
__launch_bounds__(256)
__global__ void k_gather(const float* __restrict__ H, const int* __restrict__ rp,
                         const int* __restrict__ es, const float* __restrict__ cf,
                         const float* __restrict__ di, const float* __restrict__ b,
                         float* __restrict__ out) {
    int wid = (int)(((long long)blockIdx.x * blockDim.x + threadIdx.x) >> 6);
    int lane = threadIdx.x & 63;
    if (wid >= NN) return;
    int beg = rp[wid], end = rp[wid + 1];
    float dv = di[wid];
    float2 h = *(const float2*)&H[wid * 128 + lane * 2];
    float2 bb = *(const float2*)&b[lane * 2];
    float ax = h.x * dv + bb.x;
    float ay = h.y * dv + bb.y;
    int i = beg;
    for (; i + 1 < end; i += 2) {
        int s0 = es[i], s1 = es[i + 1];
        float c0 = cf[i], c1 = cf[i + 1];
        float2 v0 = *(const float2*)&H[s0 * 128 + lane * 2];
        float2 v1 = *(const float2*)&H[s1 * 128 + lane * 2];
        ax += v0.x * c0 + v1.x * c1;
        ay += v0.y * c0 + v1.y * c1;
    }
    if (i < end) {
        int s = es[i];
        float c = cf[i];
        float2 v = *(const float2*)&H[s * 128 + lane * 2];
        ax += v.x * c;
        ay += v.y * c;
    }
    *(float2*)&out[wid * 128 + lane * 2] = make_float2(ax, ay);
}

// ---- column stats ----
__global__ void k_stats(const float* __restrict__ V, float* __restrict__ stats, int nrows) {
    int c = threadIdx.x & 127;
    int half = threadIdx.x >> 7;
    float s = 0.f, s2 = 0.f;
#pragma unroll 4
    for (int i = 0; i < 32; ++i) {
        int r = blockIdx.x * 64 + half + 2 * i;
        if (r < nrows) {
            float v = V[r * 128 + c];
            s += v;
            s2 += v * v;
        }
    }
    __shared__ float ls[256], ls2[256];
    ls[threadIdx.x] = s;
    ls2[threadIdx.x] = s2;
    __syncthreads();
    if (half == 0) {
        atomAddF(&stats[c], ls[c] + ls[c + 128]);
        atomAddF(&stats[128 + c], ls2[c] + ls2[c + 128]);
    }
}

__global__ void k_bnparams(const float* __restrict__ stats, const float* __restrict__ g,
                           const float* __restrict__ be, float* __restrict__ par) {
    int c = threadIdx.x;
    float mu = stats[c] * (1.0f / NN);
    float var = stats[128 + c] * (1.0f / NN) - mu * mu;
    float inv = rsqrtf(var + EPS);
    float sc = inv * g[c];
    par[c] = sc;
    par[128 + c] = be[c] - mu * sc;
}

__global__ void k_norm(const float* __restrict__ V, const float* __restrict__ par,
                       float* __restrict__ O, int nrows) {
    int t = blockIdx.x * blockDim.x + threadIdx.x;
    if (t >= nrows * 32) return;
    int row = t >> 5;
    int c4 = (t & 31) * 4;
    float4 v = *(const float4*)&V[row * 128 + c4];
    float4 sc = *(const float4*)&par[c4];
    float4 sh = *(const float4*)&par[128 + c4];
    float4 o;
    o.x = fmaxf(v.x * sc.x + sh.x, 0.f);
    o.y = fmaxf(v.y * sc.y + sh.y, 0.f);
    o.z = fmaxf(v.z * sc.z + sh.z, 0.f);
    o.w = fmaxf(v.w * sc.w + sh.w, 0.f);
    *(float4*)&O[row * 128 + c4] = o;
}

// ---- layer-3 matmul: Z[n][0..1] = X[n] @ W3 (128x2); one wave per node ----
__global__ void k_mm2(const float* __restrict__ X, const float* __restrict__ W3,
                      float* __restrict__ Z) {
    int wid = (int)(((long long)blockIdx.x * blockDim.x + threadIdx.x) >> 6);
    int lane = threadIdx.x & 63;
    if (wid >= NN) return;
    float2 x2 = *(const float2*)&X[wid * 128 + lane * 2];
    float4 w4 = *(const float4*)&W3[lane * 4];
    float p0 = x2.x * w4.x + x2.y * w4.z;
    float p1 = x2.x * w4.y + x2.y * w4.w;
#pragma unroll
    for (int off = 32; off; off >>= 1) {
        p0 += __shfl_xor(p0, off);
        p1 += __shfl_xor(p1, off);
    }
    if (lane == 0) *(float2*)&Z[wid * 2] = make_float2(p0, p1);
}

// ---- layer-3 CSR gather + self-loop + bias + softmax, 1 thread/node ----
__global__ void k_l3(const float* __restrict__ Z, const int* __restrict__ rp,
                     const int* __restrict__ es, const float* __restrict__ cf,
                     const float* __restrict__ di, const float* __restrict__ b3,
                     float* __restrict__ out) {
    int n = blockIdx.x * blockDim.x + threadIdx.x;
    if (n >= NN) return;
    int beg = rp[n], end = rp[n + 1];
    float dv = di[n];
    float2 z = *(const float2*)&Z[n * 2];
    float a0 = z.x * dv + b3[0];
    float a1 = z.y * dv + b3[1];
    for (int i = beg; i < end; ++i) {
        int s = es[i];
        float c = cf[i];
        float2 v = *(const float2*)&Z[s * 2];
        a0 += v.x * c;
        a1 += v.y * c;
    }
    float m = fmaxf(a0, a1);
    float e0 = __expf(a0 - m), e1 = __expf(a1 - m);
    float inv = 1.0f / (e0 + e1);
    *(float2*)&out[n * 2] = make_float2(e0 * inv, e1 * inv);
}

extern "C" void kernel_launch(void* const* d_in, const int* in_sizes, int n_in,
                              void* d_out, int out_size, void* d_ws, size_t ws_size,
                              hipStream_t stream) {
    const float* x  = (const float*)d_in[0];
    const float* W1 = (const float*)d_in[1];
    const float* b1 = (const float*)d_in[2];
    const float* g1 = (const float*)d_in[3];
    const float* be1= (const float*)d_in[4];
    const float* W2 = (const float*)d_in[5];
    const float* b2 = (const float*)d_in[6];
    const float* g2 = (const float*)d_in[7];
    const float* be2= (const float*)d_in[8];
    const float* W3 = (const float*)d_in[9];
    const float* b3 = (const float*)d_in[10];
    const int*   ei = (const int*)d_in[11];
    const int* srcp = ei;
    const int* dstp = ei + NE;
    float* out = (float*)d_out;

    float* B0    = (float*)d_ws;           // N x 128
    float* B1    = B0 + NH;                // N x 128
    float* B2    = B1 + NH;                // N x 128
    float* Z     = B2 + NH;                // N x 2
    float* dis   = Z + 2 * NN;             // N
    float* di    = dis + NN;               // N
    float* stats = di + NN;                // 256
    float* par   = stats + 256;            // 256
    float* cf    = par + 256;              // E
    int* degi    = (int*)(cf + NE);        // N
    int* rp      = degi + NN;              // N+1
    int* cursor  = rp + NN + 1;            // N
    int* bsum    = cursor + NN;            // SCAN_NB
    int* es      = bsum + 128;             // E

    const int B = 256;
    const int gE = (NE + B - 1) / B;
    const int gN = (NN + B - 1) / B;
    const int gMM = (NN + 63) / 64;
    const int gV4 = (NN * 32 + B - 1) / B;
    const int gW = (int)(((long long)NN * 64 + B - 1) / B);  // one wave/node

    // ---- CSR build ----
    hipMemsetAsync(degi, 0, NN * sizeof(int), stream);
    k_count<<<gE, B, 0, stream>>>(dstp, degi);
    k_deg<<<gN, B, 0, stream>>>(degi, dis, di);
    k_scan1<<<SCAN_NB, 256, 0, stream>>>(degi, rp, bsum);
    k_scan2<<<1, 128, 0, stream>>>(bsum);
    k_scan3<<<SCAN_NB, 256, 0, stream>>>(rp, bsum, cursor);
    k_place<<<gE, B, 0, stream>>>(srcp, dstp, dis, cursor, es, cf);

    // ---- layer 1 ----
    k_mm128<<<gMM, B, 0, stream>>>(x, W1, B1, NN);
    k_gather<<<gW, B, 0, stream>>>(B1, rp, es, cf, di, b1, B2);
    hipMemsetAsync(stats, 0, 256 * sizeof(float), stream);
    k_stats<<<gMM, B, 0, stream>>>(B2, stats, NN);
    k_bnparams<<<1, 128, 0, stream>>>(stats, g1, be1, par);
    k_norm<<<gV4, B, 0, stream>>>(B2, par, B0, NN);

    // ---- layer 2 ----
    k_mm128<<<gMM, B, 0, stream>>>(B0, W2, B1, NN);
    k_gather<<<gW, B, 0, stream>>>(B1, rp, es, cf, di, b2, B2);
    hipMemsetAsync(stats, 0, 256 * sizeof(float), stream);
    k_stats<<<gMM, B, 0, stream>>>(B2, stats, NN);
    k_bnparams<<<1, 128, 0, stream>>>(stats, g2, be2, par);
    k_norm<<<gV4, B, 0, stream>>>(B2, par, B0, NN);

    // ---- layer 3 + softmax ----
    k_mm2<<<gW, B, 0, stream>>>(B0, W3, Z);
    k_l3<<<gN, B, 0, stream>>>(Z, rp, es, cf, di, b3, out);
}

// Round 3
// 696.834 us; speedup vs baseline: 8.9296x; 1.4973x over previous
//
#include <hip/hip_runtime.h>

#define NN 100000
#define NE 1600000
#define DF 128
#define NH (NN * DF)
#define EPS 1e-5f
#define SCAN_NB 98   // ceil(NN/1024)

typedef unsigned int uint;
typedef unsigned short ushort;
typedef __attribute__((ext_vector_type(8))) short bf16x8;
typedef __attribute__((ext_vector_type(4))) float f32x4;

__device__ __forceinline__ void atomAddF(float* p, float v) {
#if defined(__gfx90a__) || defined(__gfx942__) || defined(__gfx950__)
    unsafeAtomicAdd(p, v);
#else
    atomicAdd(p, v);
#endif
}

// float -> bf16 with round-to-nearest-even
__device__ __forceinline__ ushort f2bf(float f) {
    uint u = __float_as_uint(f);
    u += 0x7fffu + ((u >> 16) & 1u);
    return (ushort)(u >> 16);
}
__device__ __forceinline__ float bflo(uint u) { return __uint_as_float(u << 16); }
__device__ __forceinline__ float bfhi(uint u) { return __uint_as_float(u & 0xffff0000u); }

// ---- integer degree count ----
__global__ void k_count(const int* __restrict__ dst, int* __restrict__ degi) {
    int e = blockIdx.x * blockDim.x + threadIdx.x;
    if (e < NE) atomicAdd(&degi[dst[e]], 1);
}

__global__ void k_deg(const int* __restrict__ degi, float* __restrict__ dis,
                      float* __restrict__ di) {
    int i = blockIdx.x * blockDim.x + threadIdx.x;
    if (i < NN) {
        float d = (float)degi[i] + 1.0f;
        dis[i] = rsqrtf(d);
        di[i] = 1.0f / d;
    }
}

// ---- prefix scan (exclusive) of degi -> row_ptr ----
__global__ void k_scan1(const int* __restrict__ in, int* __restrict__ out,
                        int* __restrict__ bsum) {
    __shared__ int sh[256];
    int base = blockIdx.x * 1024;
    int t = threadIdx.x;
    int v[4];
    int s = 0;
#pragma unroll
    for (int i = 0; i < 4; ++i) {
        int idx = base + t * 4 + i;
        v[i] = (idx < NN) ? in[idx] : 0;
        s += v[i];
    }
    sh[t] = s;
    __syncthreads();
    for (int off = 1; off < 256; off <<= 1) {
        int x = (t >= off) ? sh[t - off] : 0;
        __syncthreads();
        sh[t] += x;
        __syncthreads();
    }
    int excl = sh[t] - s;
    if (t == 255) bsum[blockIdx.x] = sh[255];
    int run = excl;
#pragma unroll
    for (int i = 0; i < 4; ++i) {
        int idx = base + t * 4 + i;
        if (idx < NN) out[idx] = run;
        run += v[i];
    }
}

__global__ void k_scan2(int* __restrict__ bsum) {
    __shared__ int sh[128];
    int t = threadIdx.x;
    int v = (t < SCAN_NB) ? bsum[t] : 0;
    sh[t] = v;
    __syncthreads();
    for (int off = 1; off < 128; off <<= 1) {
        int x = (t >= off) ? sh[t - off] : 0;
        __syncthreads();
        sh[t] += x;
        __syncthreads();
    }
    if (t < SCAN_NB) bsum[t] = sh[t] - v;
}

__global__ void k_scan3(int* __restrict__ rp, const int* __restrict__ bsum,
                        int* __restrict__ cursor) {
    int base = blockIdx.x * 1024;
    int add = bsum[blockIdx.x];
#pragma unroll
    for (int i = 0; i < 4; ++i) {
        int idx = base + threadIdx.x + i * 256;
        if (idx < NN) {
            int v = rp[idx] + add;
            rp[idx] = v;
            cursor[idx] = v;
        }
    }
    if (blockIdx.x == 0 && threadIdx.x == 0) rp[NN] = NE;
}

// ---- place edges into CSR-by-dst; per-edge coef ----
__global__ void k_place(const int* __restrict__ src, const int* __restrict__ dst,
                        const float* __restrict__ dis, int* __restrict__ cursor,
                        int* __restrict__ es, float* __restrict__ cf) {
    int e = blockIdx.x * blockDim.x + threadIdx.x;
    if (e >= NE) return;
    int s = src[e], d = dst[e];
    int p = atomicAdd(&cursor[d], 1);
    es[p] = s;
    cf[p] = dis[s] * dis[d];
}

// ---- convert x (fp32 [N][128]) -> bf16 ----
__global__ void k_cvt_x(const float* __restrict__ X, ushort* __restrict__ Xb) {
    int t = blockIdx.x * blockDim.x + threadIdx.x;
    if (t >= NH / 8) return;
    const float4* X4 = (const float4*)X;
    float4 v0 = X4[t * 2], v1 = X4[t * 2 + 1];
    uint4 o;
    o.x = (uint)f2bf(v0.x) | ((uint)f2bf(v0.y) << 16);
    o.y = (uint)f2bf(v0.z) | ((uint)f2bf(v0.w) << 16);
    o.z = (uint)f2bf(v1.x) | ((uint)f2bf(v1.y) << 16);
    o.w = (uint)f2bf(v1.z) | ((uint)f2bf(v1.w) << 16);
    ((uint4*)Xb)[t] = o;
}

// ---- convert W (fp32 [128][128], k-major) -> bf16 transposed+swizzled Wt ----
// logical Wt[n][k]; byte = n*256 + (((k>>3) ^ (n&7))<<4) + ((k&7)<<1)
__global__ void k_cvt_w(const float* __restrict__ W, ushort* __restrict__ Wt) {
    int id = blockIdx.x * blockDim.x + threadIdx.x;  // 16384
    int n = id & 127, k = id >> 7;
    ushort b = f2bf(W[id]);
    int byte = n * 256 + (((k >> 3) ^ (n & 7)) << 4) + ((k & 7) << 1);
    *(ushort*)((char*)Wt + byte) = b;
}

// ---- MFMA matmul: Y[N][128] (bf16) = Xb[N][128] (bf16) @ W[128][128] ----
// 128 rows/block, 4 waves x (2 m-tiles x 8 n-tiles), K in 4 steps of 32.
__launch_bounds__(256, 2)
__global__ void k_mm_mfma(const ushort* __restrict__ Xb, const ushort* __restrict__ Wt,
                          ushort* __restrict__ Y, int nrows) {
    __shared__ uint4 ws4[2048];  // 32 KB
    char* ws = (char*)ws4;
    const int tid = threadIdx.x;
    const int wv = tid >> 6, l = tid & 63;
    const int l15 = l & 15, l4 = l >> 4;
    const int row_base = blockIdx.x * 128 + wv * 32;
    const bool act = row_base < nrows;  // nrows % 16 == 0 -> tile-uniform guard

    // A fragments from global (issued before stage for overlap)
    bf16x8 a[2][4];
    if (act) {
#pragma unroll
        for (int mt = 0; mt < 2; ++mt)
#pragma unroll
            for (int ks = 0; ks < 4; ++ks) {
                int r = row_base + mt * 16 + l15;
                a[mt][ks] = *(const bf16x8*)&Xb[(size_t)r * 128 + ks * 32 + l4 * 8];
            }
    }
    // stage swizzled Wt (32 KB) to LDS, linear copy
    const uint4* Wg = (const uint4*)Wt;
#pragma unroll
    for (int i = 0; i < 8; ++i) ws4[tid + i * 256] = Wg[tid + i * 256];
    __syncthreads();
    if (!act) return;

    f32x4 acc[2][8];
#pragma unroll
    for (int mt = 0; mt < 2; ++mt)
#pragma unroll
        for (int nt = 0; nt < 8; ++nt) acc[mt][nt] = (f32x4){0.f, 0.f, 0.f, 0.f};

#pragma unroll
    for (int ks = 0; ks < 4; ++ks) {
        bf16x8 b[8];
#pragma unroll
        for (int nt = 0; nt < 8; ++nt) {
            int n = nt * 16 + l15;
            int chunk = (ks * 4 + l4) ^ (n & 7);
            b[nt] = *(const bf16x8*)(ws + n * 256 + chunk * 16);
        }
#pragma unroll
        for (int nt = 0; nt < 8; ++nt) {
            acc[0][nt] = __builtin_amdgcn_mfma_f32_16x16x32_bf16(a[0][ks], b[nt], acc[0][nt], 0, 0, 0);
            acc[1][nt] = __builtin_amdgcn_mfma_f32_16x16x32_bf16(a[1][ks], b[nt], acc[1][nt], 0, 0, 0);
        }
    }
    // epilogue: D[row=(l>>4)*4+r][col=l&15] per 16x16 tile
#pragma unroll
    for (int mt = 0; mt < 2; ++mt)
#pragma unroll
        for (int nt = 0; nt < 8; ++nt)
#pragma unroll
            for (int r = 0; r < 4; ++r) {
                int ro = row_base + mt * 16 + l4 * 4 + r;
                Y[(size_t)ro * 128 + nt * 16 + l15] = f2bf(acc[mt][nt][r]);
            }
}

// ---- CSR gather aggregation (bf16 H): one wave/node, fuse self-loop+bias ----
__launch_bounds__(256)
__global__ void k_gather_b(const ushort* __restrict__ H, const int* __restrict__ rp,
                           const int* __restrict__ es, const float* __restrict__ cf,
                           const float* __restrict__ di, const float* __restrict__ b,
                           float* __restrict__ out) {
    int wid = (int)(((long long)blockIdx.x * blockDim.x + threadIdx.x) >> 6);
    int lane = threadIdx.x & 63;
    if (wid >= NN) return;
    int beg = rp[wid], end = rp[wid + 1];
    float dv = di[wid];
    const uint* H32 = (const uint*)H;
    uint hu = H32[(size_t)wid * 64 + lane];
    float2 bb = *(const float2*)&b[lane * 2];
    float ax = bflo(hu) * dv + bb.x;
    float ay = bfhi(hu) * dv + bb.y;
    int i = beg;
    for (; i + 1 < end; i += 2) {
        int s0 = es[i], s1 = es[i + 1];
        float c0 = cf[i], c1 = cf[i + 1];
        uint u0 = H32[(size_t)s0 * 64 + lane];
        uint u1 = H32[(size_t)s1 * 64 + lane];
        ax += bflo(u0) * c0 + bflo(u1) * c1;
        ay += bfhi(u0) * c0 + bfhi(u1) * c1;
    }
    if (i < end) {
        int s = es[i];
        float c = cf[i];
        uint u = H32[(size_t)s * 64 + lane];
        ax += bflo(u) * c;
        ay += bfhi(u) * c;
    }
    *(float2*)&out[(size_t)wid * 128 + lane * 2] = make_float2(ax, ay);
}

// ---- column stats over fp32 agg ----
__global__ void k_stats(const float* __restrict__ V, float* __restrict__ stats, int nrows) {
    int c = threadIdx.x & 127;
    int half = threadIdx.x >> 7;
    float s = 0.f, s2 = 0.f;
#pragma unroll 4
    for (int i = 0; i < 32; ++i) {
        int r = blockIdx.x * 64 + half + 2 * i;
        if (r < nrows) {
            float v = V[(size_t)r * 128 + c];
            s += v;
            s2 += v * v;
        }
    }
    __shared__ float ls[256], ls2[256];
    ls[threadIdx.x] = s;
    ls2[threadIdx.x] = s2;
    __syncthreads();
    if (half == 0) {
        atomAddF(&stats[c], ls[c] + ls[c + 128]);
        atomAddF(&stats[128 + c], ls2[c] + ls2[c + 128]);
    }
}

__global__ void k_bnparams(const float* __restrict__ stats, const float* __restrict__ g,
                           const float* __restrict__ be, float* __restrict__ par) {
    int c = threadIdx.x;
    float mu = stats[c] * (1.0f / NN);
    float var = stats[128 + c] * (1.0f / NN) - mu * mu;
    float inv = rsqrtf(var + EPS);
    float sc = inv * g[c];
    par[c] = sc;
    par[128 + c] = be[c] - mu * sc;
}

// ---- normalize + relu, fp32 in -> bf16 out ----
__global__ void k_norm(const float* __restrict__ V, const float* __restrict__ par,
                       ushort* __restrict__ O, int nrows) {
    int t = blockIdx.x * blockDim.x + threadIdx.x;
    if (t >= nrows * 32) return;
    int row = t >> 5;
    int c4 = (t & 31) * 4;
    float4 v = *(const float4*)&V[(size_t)row * 128 + c4];
    float4 sc = *(const float4*)&par[c4];
    float4 sh = *(const float4*)&par[128 + c4];
    float o0 = fmaxf(v.x * sc.x + sh.x, 0.f);
    float o1 = fmaxf(v.y * sc.y + sh.y, 0.f);
    float o2 = fmaxf(v.z * sc.z + sh.z, 0.f);
    float o3 = fmaxf(v.w * sc.w + sh.w, 0.f);
    uint2 o;
    o.x = (uint)f2bf(o0) | ((uint)f2bf(o1) << 16);
    o.y = (uint)f2bf(o2) | ((uint)f2bf(o3) << 16);
    *(uint2*)&O[(size_t)row * 128 + c4] = o;
}

// ---- layer-3 matmul: Z[n][0..1] = B0[n] @ W3; one wave per node ----
__global__ void k_mm2(const ushort* __restrict__ X, const float* __restrict__ W3,
                      float* __restrict__ Z) {
    int wid = (int)(((long long)blockIdx.x * blockDim.x + threadIdx.x) >> 6);
    int lane = threadIdx.x & 63;
    if (wid >= NN) return;
    uint xu = ((const uint*)X)[(size_t)wid * 64 + lane];
    float x0 = bflo(xu), x1 = bfhi(xu);
    float4 w4 = *(const float4*)&W3[lane * 4];
    float p0 = x0 * w4.x + x1 * w4.z;
    float p1 = x0 * w4.y + x1 * w4.w;
#pragma unroll
    for (int off = 32; off; off >>= 1) {
        p0 += __shfl_xor(p0, off);
        p1 += __shfl_xor(p1, off);
    }
    if (lane == 0) *(float2*)&Z[wid * 2] = make_float2(p0, p1);
}

// ---- layer-3 CSR gather + self-loop + bias + softmax ----
__global__ void k_l3(const float* __restrict__ Z, const int* __restrict__ rp,
                     const int* __restrict__ es, const float* __restrict__ cf,
                     const float* __restrict__ di, const float* __restrict__ b3,
                     float* __restrict__ out) {
    int n = blockIdx.x * blockDim.x + threadIdx.x;
    if (n >= NN) return;
    int beg = rp[n], end = rp[n + 1];
    float dv = di[n];
    float2 z = *(const float2*)&Z[n * 2];
    float a0 = z.x * dv + b3[0];
    float a1 = z.y * dv + b3[1];
    for (int i = beg; i < end; ++i) {
        int s = es[i];
        float c = cf[i];
        float2 v = *(const float2*)&Z[s * 2];
        a0 += v.x * c;
        a1 += v.y * c;
    }
    float m = fmaxf(a0, a1);
    float e0 = __expf(a0 - m), e1 = __expf(a1 - m);
    float inv = 1.0f / (e0 + e1);
    *(float2*)&out[n * 2] = make_float2(e0 * inv, e1 * inv);
}

extern "C" void kernel_launch(void* const* d_in, const int* in_sizes, int n_in,
                              void* d_out, int out_size, void* d_ws, size_t ws_size,
                              hipStream_t stream) {
    const float* x  = (const float*)d_in[0];
    const float* W1 = (const float*)d_in[1];
    const float* b1 = (const float*)d_in[2];
    const float* g1 = (const float*)d_in[3];
    const float* be1= (const float*)d_in[4];
    const float* W2 = (const float*)d_in[5];
    const float* b2 = (const float*)d_in[6];
    const float* g2 = (const float*)d_in[7];
    const float* be2= (const float*)d_in[8];
    const float* W3 = (const float*)d_in[9];
    const float* b3 = (const float*)d_in[10];
    const int*   ei = (const int*)d_in[11];
    const int* srcp = ei;
    const int* dstp = ei + NE;
    float* out = (float*)d_out;

    float*  AGG = (float*)d_ws;              // N x 128 fp32
    ushort* Hb  = (ushort*)(AGG + NH);       // N x 128 bf16
    ushort* B0  = Hb + NH;                   // N x 128 bf16
    ushort* Xb  = B0 + NH;                   // N x 128 bf16
    ushort* Wt  = Xb + NH;                   // 128 x 128 bf16 (swizzled)
    float*  Z   = (float*)(Wt + 16384);      // N x 2
    float*  dis = Z + 2 * NN;                // N
    float*  di  = dis + NN;                  // N
    float*  stats = di + NN;                 // 256
    float*  par = stats + 256;               // 256
    float*  cf  = par + 256;                 // E
    int* degi   = (int*)(cf + NE);           // N
    int* rp     = degi + NN;                 // N+1
    int* cursor = rp + NN + 1;               // N
    int* bsum   = cursor + NN;               // SCAN_NB
    int* es     = bsum + 128;                // E

    const int B = 256;
    const int gE  = (NE + B - 1) / B;
    const int gN  = (NN + B - 1) / B;
    const int gMM = (NN + 127) / 128;                        // 782
    const int gST = (NN + 63) / 64;                          // 1563
    const int gV4 = (NN * 32 + B - 1) / B;
    const int gW  = (int)(((long long)NN * 64 + B - 1) / B); // one wave/node
    const int gCV = (NH / 8 + B - 1) / B;

    // ---- CSR build + conversions ----
    hipMemsetAsync(degi, 0, NN * sizeof(int), stream);
    k_count<<<gE, B, 0, stream>>>(dstp, degi);
    k_deg<<<gN, B, 0, stream>>>(degi, dis, di);
    k_scan1<<<SCAN_NB, 256, 0, stream>>>(degi, rp, bsum);
    k_scan2<<<1, 128, 0, stream>>>(bsum);
    k_scan3<<<SCAN_NB, 256, 0, stream>>>(rp, bsum, cursor);
    k_place<<<gE, B, 0, stream>>>(srcp, dstp, dis, cursor, es, cf);
    k_cvt_x<<<gCV, B, 0, stream>>>(x, Xb);

    // ---- layer 1 ----
    k_cvt_w<<<64, 256, 0, stream>>>(W1, Wt);
    k_mm_mfma<<<gMM, B, 0, stream>>>(Xb, Wt, Hb, NN);
    k_gather_b<<<gW, B, 0, stream>>>(Hb, rp, es, cf, di, b1, AGG);
    hipMemsetAsync(stats, 0, 256 * sizeof(float), stream);
    k_stats<<<gST, B, 0, stream>>>(AGG, stats, NN);
    k_bnparams<<<1, 128, 0, stream>>>(stats, g1, be1, par);
    k_norm<<<gV4, B, 0, stream>>>(AGG, par, B0, NN);

    // ---- layer 2 ----
    k_cvt_w<<<64, 256, 0, stream>>>(W2, Wt);
    k_mm_mfma<<<gMM, B, 0, stream>>>(B0, Wt, Hb, NN);
    k_gather_b<<<gW, B, 0, stream>>>(Hb, rp, es, cf, di, b2, AGG);
    hipMemsetAsync(stats, 0, 256 * sizeof(float), stream);
    k_stats<<<gST, B, 0, stream>>>(AGG, stats, NN);
    k_bnparams<<<1, 128, 0, stream>>>(stats, g2, be2, par);
    k_norm<<<gV4, B, 0, stream>>>(AGG, par, B0, NN);

    // ---- layer 3 + softmax ----
    k_mm2<<<gW, B, 0, stream>>>(B0, W3, Z);
    k_l3<<<gN, B, 0, stream>>>(Z, rp, es, cf, di, b3, out);
}

// Round 4
// 616.456 us; speedup vs baseline: 10.0939x; 1.1304x over previous
//
#include <hip/hip_runtime.h>

#define NN 100000
#define NE 1600000
#define DF 128
#define NH (NN * DF)
#define EPS 1e-5f
#define SCAN_NB 98   // ceil(NN/1024)

typedef unsigned int uint;
typedef unsigned short ushort;
typedef __attribute__((ext_vector_type(8))) short bf16x8;
typedef __attribute__((ext_vector_type(4))) float f32x4;

__device__ __forceinline__ void atomAddF(float* p, float v) {
#if defined(__gfx90a__) || defined(__gfx942__) || defined(__gfx950__)
    unsafeAtomicAdd(p, v);
#else
    atomicAdd(p, v);
#endif
}

// float -> bf16 round-to-nearest-even
__device__ __forceinline__ ushort f2bf(float f) {
    uint u = __float_as_uint(f);
    u += 0x7fffu + ((u >> 16) & 1u);
    return (ushort)(u >> 16);
}
__device__ __forceinline__ float bflo(uint u) { return __uint_as_float(u << 16); }
__device__ __forceinline__ float bfhi(uint u) { return __uint_as_float(u & 0xffff0000u); }

// ---- integer degree count ----
__global__ void k_count(const int* __restrict__ dst, int* __restrict__ degi) {
    int e = blockIdx.x * blockDim.x + threadIdx.x;
    if (e < NE) atomicAdd(&degi[dst[e]], 1);
}

__global__ void k_deg(const int* __restrict__ degi, float* __restrict__ dis,
                      float* __restrict__ di) {
    int i = blockIdx.x * blockDim.x + threadIdx.x;
    if (i < NN) {
        float d = (float)degi[i] + 1.0f;
        dis[i] = rsqrtf(d);
        di[i] = 1.0f / d;
    }
}

// ---- prefix scan (exclusive) of degi -> row_ptr ----
__global__ void k_scan1(const int* __restrict__ in, int* __restrict__ out,
                        int* __restrict__ bsum) {
    __shared__ int sh[256];
    int base = blockIdx.x * 1024;
    int t = threadIdx.x;
    int v[4];
    int s = 0;
#pragma unroll
    for (int i = 0; i < 4; ++i) {
        int idx = base + t * 4 + i;
        v[i] = (idx < NN) ? in[idx] : 0;
        s += v[i];
    }
    sh[t] = s;
    __syncthreads();
    for (int off = 1; off < 256; off <<= 1) {
        int x = (t >= off) ? sh[t - off] : 0;
        __syncthreads();
        sh[t] += x;
        __syncthreads();
    }
    int excl = sh[t] - s;
    if (t == 255) bsum[blockIdx.x] = sh[255];
    int run = excl;
#pragma unroll
    for (int i = 0; i < 4; ++i) {
        int idx = base + t * 4 + i;
        if (idx < NN) out[idx] = run;
        run += v[i];
    }
}

__global__ void k_scan2(int* __restrict__ bsum, float* __restrict__ stats) {
    __shared__ int sh[128];
    int t = threadIdx.x;
    // zero both layers' stats buffers (512 floats)
#pragma unroll
    for (int i = 0; i < 4; ++i) stats[t * 4 + i] = 0.0f;
    int v = (t < SCAN_NB) ? bsum[t] : 0;
    sh[t] = v;
    __syncthreads();
    for (int off = 1; off < 128; off <<= 1) {
        int x = (t >= off) ? sh[t - off] : 0;
        __syncthreads();
        sh[t] += x;
        __syncthreads();
    }
    if (t < SCAN_NB) bsum[t] = sh[t] - v;
}

__global__ void k_scan3(int* __restrict__ rp, const int* __restrict__ bsum,
                        int* __restrict__ cursor) {
    int base = blockIdx.x * 1024;
    int add = bsum[blockIdx.x];
#pragma unroll
    for (int i = 0; i < 4; ++i) {
        int idx = base + threadIdx.x + i * 256;
        if (idx < NN) {
            int v = rp[idx] + add;
            rp[idx] = v;
            cursor[idx] = v;
        }
    }
    if (blockIdx.x == 0 && threadIdx.x == 0) rp[NN] = NE;
}

// ---- place edges into CSR-by-dst; packed (src, coef) single 8B store ----
__global__ void k_place(const int* __restrict__ src, const int* __restrict__ dst,
                        const float* __restrict__ dis, int* __restrict__ cursor,
                        uint2* __restrict__ ec) {
    int e = blockIdx.x * blockDim.x + threadIdx.x;
    if (e >= NE) return;
    int s = src[e], d = dst[e];
    int p = atomicAdd(&cursor[d], 1);
    ec[p] = make_uint2((uint)s, __float_as_uint(dis[s] * dis[d]));
}

// ---- convert x (fp32 [N][128]) -> bf16 ----
__global__ void k_cvt_x(const float* __restrict__ X, ushort* __restrict__ Xb) {
    int t = blockIdx.x * blockDim.x + threadIdx.x;
    if (t >= NH / 8) return;
    const float4* X4 = (const float4*)X;
    float4 v0 = X4[t * 2], v1 = X4[t * 2 + 1];
    uint4 o;
    o.x = (uint)f2bf(v0.x) | ((uint)f2bf(v0.y) << 16);
    o.y = (uint)f2bf(v0.z) | ((uint)f2bf(v0.w) << 16);
    o.z = (uint)f2bf(v1.x) | ((uint)f2bf(v1.y) << 16);
    o.w = (uint)f2bf(v1.z) | ((uint)f2bf(v1.w) << 16);
    ((uint4*)Xb)[t] = o;
}

// ---- convert W (fp32 [128][128]) -> bf16 transposed+swizzled ----
__global__ void k_cvt_w(const float* __restrict__ W, ushort* __restrict__ Wt) {
    int id = blockIdx.x * blockDim.x + threadIdx.x;
    int n = id & 127, k = id >> 7;
    ushort b = f2bf(W[id]);
    int byte = n * 256 + (((k >> 3) ^ (n & 7)) << 4) + ((k & 7) << 1);
    *(ushort*)((char*)Wt + byte) = b;
}

// ---- MFMA matmul: Y[N][128] (bf16) = Xb @ W ----
__launch_bounds__(256, 2)
__global__ void k_mm_mfma(const ushort* __restrict__ Xb, const ushort* __restrict__ Wt,
                          ushort* __restrict__ Y, int nrows) {
    __shared__ uint4 ws4[2048];  // 32 KB
    char* ws = (char*)ws4;
    const int tid = threadIdx.x;
    const int wv = tid >> 6, l = tid & 63;
    const int l15 = l & 15, l4 = l >> 4;
    const int row_base = blockIdx.x * 128 + wv * 32;
    const bool act = row_base < nrows;

    bf16x8 a[2][4];
    if (act) {
#pragma unroll
        for (int mt = 0; mt < 2; ++mt)
#pragma unroll
            for (int ks = 0; ks < 4; ++ks) {
                int r = row_base + mt * 16 + l15;
                a[mt][ks] = *(const bf16x8*)&Xb[(size_t)r * 128 + ks * 32 + l4 * 8];
            }
    }
    const uint4* Wg = (const uint4*)Wt;
#pragma unroll
    for (int i = 0; i < 8; ++i) ws4[tid + i * 256] = Wg[tid + i * 256];
    __syncthreads();
    if (!act) return;

    f32x4 acc[2][8];
#pragma unroll
    for (int mt = 0; mt < 2; ++mt)
#pragma unroll
        for (int nt = 0; nt < 8; ++nt) acc[mt][nt] = (f32x4){0.f, 0.f, 0.f, 0.f};

#pragma unroll
    for (int ks = 0; ks < 4; ++ks) {
        bf16x8 b[8];
#pragma unroll
        for (int nt = 0; nt < 8; ++nt) {
            int n = nt * 16 + l15;
            int chunk = (ks * 4 + l4) ^ (n & 7);
            b[nt] = *(const bf16x8*)(ws + n * 256 + chunk * 16);
        }
#pragma unroll
        for (int nt = 0; nt < 8; ++nt) {
            acc[0][nt] = __builtin_amdgcn_mfma_f32_16x16x32_bf16(a[0][ks], b[nt], acc[0][nt], 0, 0, 0);
            acc[1][nt] = __builtin_amdgcn_mfma_f32_16x16x32_bf16(a[1][ks], b[nt], acc[1][nt], 0, 0, 0);
        }
    }
#pragma unroll
    for (int mt = 0; mt < 2; ++mt)
#pragma unroll
        for (int nt = 0; nt < 8; ++nt)
#pragma unroll
            for (int r = 0; r < 4; ++r) {
                int ro = row_base + mt * 16 + l4 * 4 + r;
                Y[(size_t)ro * 128 + nt * 16 + l15] = f2bf(acc[mt][nt][r]);
            }
}

// ---- CSR gather (bf16 H): one wave/node, 4-deep MLP, fuse self-loop+bias ----
__launch_bounds__(256)
__global__ void k_gather_b(const ushort* __restrict__ H, const int* __restrict__ rp,
                           const uint2* __restrict__ ec, const float* __restrict__ di,
                           const float* __restrict__ b, float* __restrict__ out) {
    int wid = (int)(((long long)blockIdx.x * blockDim.x + threadIdx.x) >> 6);
    int lane = threadIdx.x & 63;
    if (wid >= NN) return;
    int beg = rp[wid], end = rp[wid + 1];
    float dv = di[wid];
    const uint* H32 = (const uint*)H;
    uint hu = H32[(size_t)wid * 64 + lane];
    float2 bb = *(const float2*)&b[lane * 2];
    float ax = bflo(hu) * dv + bb.x;
    float ay = bfhi(hu) * dv + bb.y;
    int i = beg;
    for (; i + 3 < end; i += 4) {
        uint2 e0 = ec[i], e1 = ec[i + 1], e2 = ec[i + 2], e3 = ec[i + 3];
        uint u0 = H32[(size_t)e0.x * 64 + lane];
        uint u1 = H32[(size_t)e1.x * 64 + lane];
        uint u2 = H32[(size_t)e2.x * 64 + lane];
        uint u3 = H32[(size_t)e3.x * 64 + lane];
        float c0 = __uint_as_float(e0.y), c1 = __uint_as_float(e1.y);
        float c2 = __uint_as_float(e2.y), c3 = __uint_as_float(e3.y);
        ax += bflo(u0) * c0 + bflo(u1) * c1 + bflo(u2) * c2 + bflo(u3) * c3;
        ay += bfhi(u0) * c0 + bfhi(u1) * c1 + bfhi(u2) * c2 + bfhi(u3) * c3;
    }
    for (; i < end; ++i) {
        uint2 e0 = ec[i];
        uint u = H32[(size_t)e0.x * 64 + lane];
        float c = __uint_as_float(e0.y);
        ax += bflo(u) * c;
        ay += bfhi(u) * c;
    }
    *(float2*)&out[(size_t)wid * 128 + lane * 2] = make_float2(ax, ay);
}

// ---- column stats ----
__global__ void k_stats(const float* __restrict__ V, float* __restrict__ stats, int nrows) {
    int c = threadIdx.x & 127;
    int half = threadIdx.x >> 7;
    float s = 0.f, s2 = 0.f;
#pragma unroll 4
    for (int i = 0; i < 32; ++i) {
        int r = blockIdx.x * 64 + half + 2 * i;
        if (r < nrows) {
            float v = V[(size_t)r * 128 + c];
            s += v;
            s2 += v * v;
        }
    }
    __shared__ float ls[256], ls2[256];
    ls[threadIdx.x] = s;
    ls2[threadIdx.x] = s2;
    __syncthreads();
    if (half == 0) {
        atomAddF(&stats[c], ls[c] + ls[c + 128]);
        atomAddF(&stats[128 + c], ls2[c] + ls2[c + 128]);
    }
}

__global__ void k_bnparams(const float* __restrict__ stats, const float* __restrict__ g,
                           const float* __restrict__ be, float* __restrict__ par) {
    int c = threadIdx.x;
    float mu = stats[c] * (1.0f / NN);
    float var = stats[128 + c] * (1.0f / NN) - mu * mu;
    float inv = rsqrtf(var + EPS);
    float sc = inv * g[c];
    par[c] = sc;
    par[128 + c] = be[c] - mu * sc;
}

// ---- normalize + relu, fp32 in -> bf16 out ----
__global__ void k_norm(const float* __restrict__ V, const float* __restrict__ par,
                       ushort* __restrict__ O, int nrows) {
    int t = blockIdx.x * blockDim.x + threadIdx.x;
    if (t >= nrows * 32) return;
    int row = t >> 5;
    int c4 = (t & 31) * 4;
    float4 v = *(const float4*)&V[(size_t)row * 128 + c4];
    float4 sc = *(const float4*)&par[c4];
    float4 sh = *(const float4*)&par[128 + c4];
    float o0 = fmaxf(v.x * sc.x + sh.x, 0.f);
    float o1 = fmaxf(v.y * sc.y + sh.y, 0.f);
    float o2 = fmaxf(v.z * sc.z + sh.z, 0.f);
    float o3 = fmaxf(v.w * sc.w + sh.w, 0.f);
    uint2 o;
    o.x = (uint)f2bf(o0) | ((uint)f2bf(o1) << 16);
    o.y = (uint)f2bf(o2) | ((uint)f2bf(o3) << 16);
    *(uint2*)&O[(size_t)row * 128 + c4] = o;
}

// ---- layer-3 matmul: one wave per node ----
__global__ void k_mm2(const ushort* __restrict__ X, const float* __restrict__ W3,
                      float* __restrict__ Z) {
    int wid = (int)(((long long)blockIdx.x * blockDim.x + threadIdx.x) >> 6);
    int lane = threadIdx.x & 63;
    if (wid >= NN) return;
    uint xu = ((const uint*)X)[(size_t)wid * 64 + lane];
    float x0 = bflo(xu), x1 = bfhi(xu);
    float4 w4 = *(const float4*)&W3[lane * 4];
    float p0 = x0 * w4.x + x1 * w4.z;
    float p1 = x0 * w4.y + x1 * w4.w;
#pragma unroll
    for (int off = 32; off; off >>= 1) {
        p0 += __shfl_xor(p0, off);
        p1 += __shfl_xor(p1, off);
    }
    if (lane == 0) *(float2*)&Z[wid * 2] = make_float2(p0, p1);
}

// ---- layer-3 CSR gather + softmax ----
__global__ void k_l3(const float* __restrict__ Z, const int* __restrict__ rp,
                     const uint2* __restrict__ ec, const float* __restrict__ di,
                     const float* __restrict__ b3, float* __restrict__ out) {
    int n = blockIdx.x * blockDim.x + threadIdx.x;
    if (n >= NN) return;
    int beg = rp[n], end = rp[n + 1];
    float dv = di[n];
    float2 z = *(const float2*)&Z[n * 2];
    float a0 = z.x * dv + b3[0];
    float a1 = z.y * dv + b3[1];
    for (int i = beg; i < end; ++i) {
        uint2 e0 = ec[i];
        float c = __uint_as_float(e0.y);
        float2 v = *(const float2*)&Z[e0.x * 2];
        a0 += v.x * c;
        a1 += v.y * c;
    }
    float m = fmaxf(a0, a1);
    float e0 = __expf(a0 - m), e1 = __expf(a1 - m);
    float inv = 1.0f / (e0 + e1);
    *(float2*)&out[n * 2] = make_float2(e0 * inv, e1 * inv);
}

extern "C" void kernel_launch(void* const* d_in, const int* in_sizes, int n_in,
                              void* d_out, int out_size, void* d_ws, size_t ws_size,
                              hipStream_t stream) {
    const float* x  = (const float*)d_in[0];
    const float* W1 = (const float*)d_in[1];
    const float* b1 = (const float*)d_in[2];
    const float* g1 = (const float*)d_in[3];
    const float* be1= (const float*)d_in[4];
    const float* W2 = (const float*)d_in[5];
    const float* b2 = (const float*)d_in[6];
    const float* g2 = (const float*)d_in[7];
    const float* be2= (const float*)d_in[8];
    const float* W3 = (const float*)d_in[9];
    const float* b3 = (const float*)d_in[10];
    const int*   ei = (const int*)d_in[11];
    const int* srcp = ei;
    const int* dstp = ei + NE;
    float* out = (float*)d_out;

    char* wsp = (char*)d_ws;
    auto alloc = [&](size_t bytes) {
        char* p = wsp;
        wsp += (bytes + 255) & ~(size_t)255;
        return p;
    };
    float*  AGG  = (float*)alloc((size_t)NH * 4);
    ushort* Hb   = (ushort*)alloc((size_t)NH * 2);
    ushort* B0   = (ushort*)alloc((size_t)NH * 2);
    ushort* Xb   = (ushort*)alloc((size_t)NH * 2);
    ushort* Wt   = (ushort*)alloc(16384 * 2);
    float*  Z    = (float*)alloc((size_t)2 * NN * 4);
    float*  dis  = (float*)alloc((size_t)NN * 4);
    float*  di   = (float*)alloc((size_t)NN * 4);
    float*  stats= (float*)alloc(512 * 4);
    float*  par  = (float*)alloc(256 * 4);
    uint2*  ec   = (uint2*)alloc((size_t)NE * 8);
    int*    degi = (int*)alloc((size_t)NN * 4);
    int*    rp   = (int*)alloc((size_t)(NN + 1) * 4);
    int*    cursor=(int*)alloc((size_t)NN * 4);
    int*    bsum = (int*)alloc(128 * 4);

    const int B = 256;
    const int gE  = (NE + B - 1) / B;
    const int gN  = (NN + B - 1) / B;
    const int gMM = (NN + 127) / 128;
    const int gST = (NN + 63) / 64;
    const int gV4 = (NN * 32 + B - 1) / B;
    const int gW  = (int)(((long long)NN * 64 + B - 1) / B);
    const int gCV = (NH / 8 + B - 1) / B;

    // ---- CSR build + conversions ----
    hipMemsetAsync(degi, 0, NN * sizeof(int), stream);
    k_count<<<gE, B, 0, stream>>>(dstp, degi);
    k_deg<<<gN, B, 0, stream>>>(degi, dis, di);
    k_scan1<<<SCAN_NB, 256, 0, stream>>>(degi, rp, bsum);
    k_scan2<<<1, 128, 0, stream>>>(bsum, stats);
    k_scan3<<<SCAN_NB, 256, 0, stream>>>(rp, bsum, cursor);
    k_place<<<gE, B, 0, stream>>>(srcp, dstp, dis, cursor, ec);
    k_cvt_x<<<gCV, B, 0, stream>>>(x, Xb);

    // ---- layer 1 ----
    k_cvt_w<<<64, 256, 0, stream>>>(W1, Wt);
    k_mm_mfma<<<gMM, B, 0, stream>>>(Xb, Wt, Hb, NN);
    k_gather_b<<<gW, B, 0, stream>>>(Hb, rp, ec, di, b1, AGG);
    k_stats<<<gST, B, 0, stream>>>(AGG, stats, NN);
    k_bnparams<<<1, 128, 0, stream>>>(stats, g1, be1, par);
    k_norm<<<gV4, B, 0, stream>>>(AGG, par, B0, NN);

    // ---- layer 2 ----
    k_cvt_w<<<64, 256, 0, stream>>>(W2, Wt);
    k_mm_mfma<<<gMM, B, 0, stream>>>(B0, Wt, Hb, NN);
    k_gather_b<<<gW, B, 0, stream>>>(Hb, rp, ec, di, b2, AGG);
    k_stats<<<gST, B, 0, stream>>>(AGG, stats + 256, NN);
    k_bnparams<<<1, 128, 0, stream>>>(stats + 256, g2, be2, par);
    k_norm<<<gV4, B, 0, stream>>>(AGG, par, B0, NN);

    // ---- layer 3 + softmax ----
    k_mm2<<<gW, B, 0, stream>>>(B0, W3, Z);
    k_l3<<<gN, B, 0, stream>>>(Z, rp, ec, di, b3, out);
}

// Round 5
// 558.279 us; speedup vs baseline: 11.1457x; 1.1042x over previous
//
#include <hip/hip_runtime.h>

#define NN 100000
#define NE 1600000
#define DF 128
#define NH (NN * DF)
#define EPS 1e-5f
#define NB 196        // buckets of 512 dst nodes
#define CAP 10240     // per-bucket edge capacity (mean 8192, sd ~90)
#define EPB 8192      // edges per k_part block

typedef unsigned int uint;
typedef unsigned short ushort;
typedef __attribute__((ext_vector_type(8))) short bf16x8;
typedef __attribute__((ext_vector_type(4))) float f32x4;

__device__ __forceinline__ void atomAddF(float* p, float v) {
#if defined(__gfx90a__) || defined(__gfx942__) || defined(__gfx950__)
    unsafeAtomicAdd(p, v);
#else
    atomicAdd(p, v);
#endif
}

__device__ __forceinline__ ushort f2bf(float f) {
    uint u = __float_as_uint(f);
    u += 0x7fffu + ((u >> 16) & 1u);
    return (ushort)(u >> 16);
}
__device__ __forceinline__ float bflo(uint u) { return __uint_as_float(u << 16); }
__device__ __forceinline__ float bfhi(uint u) { return __uint_as_float(u & 0xffff0000u); }

// ---- pass B: partition edges into 196 bucket lists, packed (src | dloc<<17) ----
__launch_bounds__(256)
__global__ void k_part(const int* __restrict__ src, const int* __restrict__ dst,
                       int* __restrict__ gcur, uint* __restrict__ ebuf) {
    __shared__ int cnt[NB], base[NB];
    int t = threadIdx.x;
    if (t < NB) cnt[t] = 0;
    __syncthreads();
    int e0 = blockIdx.x * EPB;
#pragma unroll
    for (int i = 0; i < EPB / 256; ++i) {
        int e = e0 + i * 256 + t;
        if (e < NE) atomicAdd(&cnt[dst[e] >> 9], 1);
    }
    __syncthreads();
    if (t < NB) {
        base[t] = atomicAdd(&gcur[t], cnt[t]);
        cnt[t] = 0;
    }
    __syncthreads();
#pragma unroll
    for (int i = 0; i < EPB / 256; ++i) {
        int e = e0 + i * 256 + t;
        if (e < NE) {
            int d = dst[e];
            int b = d >> 9;
            int off = atomicAdd(&cnt[b], 1);
            ebuf[b * CAP + base[b] + off] = (uint)src[e] | ((uint)(d & 511) << 17);
        }
    }
}

// ---- scan bucket totals -> bstart; also zero stats, set rp[NN] ----
__global__ void k_bscan(const int* __restrict__ gcur, int* __restrict__ bstart,
                        float* __restrict__ stats, int* __restrict__ rp) {
    __shared__ int sh[256];
    int t = threadIdx.x;
    stats[t] = 0.f;
    stats[t + 256] = 0.f;
    int v = (t < NB) ? gcur[t] : 0;
    sh[t] = v;
    __syncthreads();
    for (int off = 1; off < 256; off <<= 1) {
        int x = (t >= off) ? sh[t - off] : 0;
        __syncthreads();
        sh[t] += x;
        __syncthreads();
    }
    if (t < NB) bstart[t] = sh[t] - v;
    if (t == 0) {
        bstart[NB] = NE;
        rp[NN] = NE;
    }
}

// ---- pass C1: per bucket, per-node degree -> dis/di/rp ----
__launch_bounds__(256)
__global__ void k_c1(const uint* __restrict__ ebuf, const int* __restrict__ gcur,
                     const int* __restrict__ bstart, float* __restrict__ dis,
                     float* __restrict__ di, int* __restrict__ rp) {
    __shared__ int ncnt[512];
    __shared__ int ssum[256];
    int b = blockIdx.x, t = threadIdx.x;
    ncnt[t] = 0;
    ncnt[t + 256] = 0;
    __syncthreads();
    int ne = gcur[b];
    const uint* eb = ebuf + (size_t)b * CAP;
    for (int e = t; e < ne; e += 256) atomicAdd(&ncnt[eb[e] >> 17], 1);
    __syncthreads();
    int a0 = ncnt[t * 2], a1 = ncnt[t * 2 + 1];
    int ps = a0 + a1;
    ssum[t] = ps;
    __syncthreads();
    for (int off = 1; off < 256; off <<= 1) {
        int x = (t >= off) ? ssum[t - off] : 0;
        __syncthreads();
        ssum[t] += x;
        __syncthreads();
    }
    int excl = ssum[t] - ps;
    int base = bstart[b];
    int g0 = b * 512 + t * 2;
    if (g0 < NN) {
        rp[g0] = base + excl;
        float d = (float)a0 + 1.0f;
        dis[g0] = rsqrtf(d);
        di[g0] = 1.0f / d;
    }
    if (g0 + 1 < NN) {
        rp[g0 + 1] = base + excl + a0;
        float d = (float)a1 + 1.0f;
        dis[g0 + 1] = rsqrtf(d);
        di[g0 + 1] = 1.0f / d;
    }
}

// ---- pass C2: per bucket, place (src, coef) into CSR window (L2-combined) ----
__launch_bounds__(256)
__global__ void k_c2(const uint* __restrict__ ebuf, const int* __restrict__ gcur,
                     const int* __restrict__ rp, const float* __restrict__ dis,
                     uint2* __restrict__ ec) {
    __shared__ int cur[512];
    __shared__ float dl[512];
    int b = blockIdx.x, t = threadIdx.x;
#pragma unroll
    for (int i = 0; i < 2; ++i) {
        int g = b * 512 + t + i * 256;
        if (g < NN) {
            cur[t + i * 256] = rp[g];
            dl[t + i * 256] = dis[g];
        }
    }
    __syncthreads();
    int ne = gcur[b];
    const uint* eb = ebuf + (size_t)b * CAP;
    for (int e = t; e < ne; e += 256) {
        uint u = eb[e];
        int s = u & 0x1FFFF;
        int dloc = u >> 17;
        int pos = atomicAdd(&cur[dloc], 1);
        ec[pos] = make_uint2((uint)s, __float_as_uint(dis[s] * dl[dloc]));
    }
}

// ---- convert x -> bf16 ----
__global__ void k_cvt_x(const float* __restrict__ X, ushort* __restrict__ Xb) {
    int t = blockIdx.x * blockDim.x + threadIdx.x;
    if (t >= NH / 8) return;
    const float4* X4 = (const float4*)X;
    float4 v0 = X4[t * 2], v1 = X4[t * 2 + 1];
    uint4 o;
    o.x = (uint)f2bf(v0.x) | ((uint)f2bf(v0.y) << 16);
    o.y = (uint)f2bf(v0.z) | ((uint)f2bf(v0.w) << 16);
    o.z = (uint)f2bf(v1.x) | ((uint)f2bf(v1.y) << 16);
    o.w = (uint)f2bf(v1.z) | ((uint)f2bf(v1.w) << 16);
    ((uint4*)Xb)[t] = o;
}

// ---- convert W -> bf16 transposed+swizzled ----
__global__ void k_cvt_w(const float* __restrict__ W, ushort* __restrict__ Wt) {
    int id = blockIdx.x * blockDim.x + threadIdx.x;
    int n = id & 127, k = id >> 7;
    ushort b = f2bf(W[id]);
    int byte = n * 256 + (((k >> 3) ^ (n & 7)) << 4) + ((k & 7) << 1);
    *(ushort*)((char*)Wt + byte) = b;
}

// ---- MFMA matmul, optional fused BN-affine+ReLU on the A operand ----
__launch_bounds__(256, 2)
__global__ void k_mm_mfma(const ushort* __restrict__ Xb, const ushort* __restrict__ Wt,
                          const float* __restrict__ par, ushort* __restrict__ Y,
                          int nrows) {
    __shared__ uint4 ws4[2048];  // 32 KB
    char* ws = (char*)ws4;
    const int tid = threadIdx.x;
    const int wv = tid >> 6, l = tid & 63;
    const int l15 = l & 15, l4 = l >> 4;
    const int row_base = blockIdx.x * 128 + wv * 32;
    const bool act = row_base < nrows;

    bf16x8 a[2][4];
    if (act) {
#pragma unroll
        for (int mt = 0; mt < 2; ++mt)
#pragma unroll
            for (int ks = 0; ks < 4; ++ks) {
                int r = row_base + mt * 16 + l15;
                a[mt][ks] = *(const bf16x8*)&Xb[(size_t)r * 128 + ks * 32 + l4 * 8];
            }
        if (par) {
#pragma unroll
            for (int ks = 0; ks < 4; ++ks) {
                int k0 = ks * 32 + l4 * 8;
                float4 sa = *(const float4*)&par[k0];
                float4 sb = *(const float4*)&par[k0 + 4];
                float4 ha = *(const float4*)&par[128 + k0];
                float4 hb = *(const float4*)&par[128 + k0 + 4];
                float sc[8] = {sa.x, sa.y, sa.z, sa.w, sb.x, sb.y, sb.z, sb.w};
                float sh[8] = {ha.x, ha.y, ha.z, ha.w, hb.x, hb.y, hb.z, hb.w};
#pragma unroll
                for (int mt = 0; mt < 2; ++mt)
#pragma unroll
                    for (int j = 0; j < 8; ++j) {
                        float f = __uint_as_float(((uint)(ushort)a[mt][ks][j]) << 16);
                        f = fmaxf(f * sc[j] + sh[j], 0.0f);
                        a[mt][ks][j] = (short)f2bf(f);
                    }
            }
        }
    }
    const uint4* Wg = (const uint4*)Wt;
#pragma unroll
    for (int i = 0; i < 8; ++i) ws4[tid + i * 256] = Wg[tid + i * 256];
    __syncthreads();
    if (!act) return;

    f32x4 acc[2][8];
#pragma unroll
    for (int mt = 0; mt < 2; ++mt)
#pragma unroll
        for (int nt = 0; nt < 8; ++nt) acc[mt][nt] = (f32x4){0.f, 0.f, 0.f, 0.f};

#pragma unroll
    for (int ks = 0; ks < 4; ++ks) {
        bf16x8 b[8];
#pragma unroll
        for (int nt = 0; nt < 8; ++nt) {
            int n = nt * 16 + l15;
            int chunk = (ks * 4 + l4) ^ (n & 7);
            b[nt] = *(const bf16x8*)(ws + n * 256 + chunk * 16);
        }
#pragma unroll
        for (int nt = 0; nt < 8; ++nt) {
            acc[0][nt] = __builtin_amdgcn_mfma_f32_16x16x32_bf16(a[0][ks], b[nt], acc[0][nt], 0, 0, 0);
            acc[1][nt] = __builtin_amdgcn_mfma_f32_16x16x32_bf16(a[1][ks], b[nt], acc[1][nt], 0, 0, 0);
        }
    }
#pragma unroll
    for (int mt = 0; mt < 2; ++mt)
#pragma unroll
        for (int nt = 0; nt < 8; ++nt)
#pragma unroll
            for (int r = 0; r < 4; ++r) {
                int ro = row_base + mt * 16 + l4 * 4 + r;
                Y[(size_t)ro * 128 + nt * 16 + l15] = f2bf(acc[mt][nt][r]);
            }
}

// ---- CSR gather (bf16 H) -> bf16 agg; one wave/node, 4-deep unroll ----
__launch_bounds__(256)
__global__ void k_gather_b(const ushort* __restrict__ H, const int* __restrict__ rp,
                           const uint2* __restrict__ ec, const float* __restrict__ di,
                           const float* __restrict__ b, uint* __restrict__ outb) {
    int wid = (int)(((long long)blockIdx.x * blockDim.x + threadIdx.x) >> 6);
    int lane = threadIdx.x & 63;
    if (wid >= NN) return;
    int beg = rp[wid], end = rp[wid + 1];
    float dv = di[wid];
    const uint* H32 = (const uint*)H;
    uint hu = H32[(size_t)wid * 64 + lane];
    float2 bb = *(const float2*)&b[lane * 2];
    float ax = bflo(hu) * dv + bb.x;
    float ay = bfhi(hu) * dv + bb.y;
    int i = beg;
    for (; i + 3 < end; i += 4) {
        uint2 e0 = ec[i], e1 = ec[i + 1], e2 = ec[i + 2], e3 = ec[i + 3];
        uint u0 = H32[(size_t)e0.x * 64 + lane];
        uint u1 = H32[(size_t)e1.x * 64 + lane];
        uint u2 = H32[(size_t)e2.x * 64 + lane];
        uint u3 = H32[(size_t)e3.x * 64 + lane];
        float c0 = __uint_as_float(e0.y), c1 = __uint_as_float(e1.y);
        float c2 = __uint_as_float(e2.y), c3 = __uint_as_float(e3.y);
        ax += bflo(u0) * c0 + bflo(u1) * c1 + bflo(u2) * c2 + bflo(u3) * c3;
        ay += bfhi(u0) * c0 + bfhi(u1) * c1 + bfhi(u2) * c2 + bfhi(u3) * c3;
    }
    for (; i < end; ++i) {
        uint2 e0 = ec[i];
        uint u = H32[(size_t)e0.x * 64 + lane];
        float c = __uint_as_float(e0.y);
        ax += bflo(u) * c;
        ay += bfhi(u) * c;
    }
    outb[(size_t)wid * 64 + lane] = (uint)f2bf(ax) | ((uint)f2bf(ay) << 16);
}

// ---- column stats over bf16 agg ----
__global__ void k_statsb(const uint* __restrict__ V, float* __restrict__ stats, int nrows) {
    int cp = threadIdx.x & 63;
    int q = threadIdx.x >> 6;
    float s0 = 0.f, s1 = 0.f, q0 = 0.f, q1 = 0.f;
#pragma unroll 4
    for (int i = 0; i < 16; ++i) {
        int r = blockIdx.x * 64 + q + 4 * i;
        if (r < nrows) {
            uint u = V[(size_t)r * 64 + cp];
            float lo = bflo(u), hi = bfhi(u);
            s0 += lo;
            q0 += lo * lo;
            s1 += hi;
            q1 += hi * hi;
        }
    }
    __shared__ float L[4][256];
    L[0][threadIdx.x] = s0;
    L[1][threadIdx.x] = s1;
    L[2][threadIdx.x] = q0;
    L[3][threadIdx.x] = q1;
    __syncthreads();
    if (q == 0) {
        float a = 0.f, b = 0.f, c = 0.f, d = 0.f;
#pragma unroll
        for (int j = 0; j < 4; ++j) {
            a += L[0][cp + j * 64];
            b += L[1][cp + j * 64];
            c += L[2][cp + j * 64];
            d += L[3][cp + j * 64];
        }
        atomAddF(&stats[2 * cp], a);
        atomAddF(&stats[2 * cp + 1], b);
        atomAddF(&stats[128 + 2 * cp], c);
        atomAddF(&stats[128 + 2 * cp + 1], d);
    }
}

__global__ void k_bnparams(const float* __restrict__ stats, const float* __restrict__ g,
                           const float* __restrict__ be, float* __restrict__ par) {
    int c = threadIdx.x;
    float mu = stats[c] * (1.0f / NN);
    float var = stats[128 + c] * (1.0f / NN) - mu * mu;
    float inv = rsqrtf(var + EPS);
    float sc = inv * g[c];
    par[c] = sc;
    par[128 + c] = be[c] - mu * sc;
}

// ---- layer-3: affine+relu on bf16 agg, dot W3; one wave per node ----
__global__ void k_mm2(const uint* __restrict__ X, const float* __restrict__ W3,
                      const float* __restrict__ par, float* __restrict__ Z) {
    int wid = (int)(((long long)blockIdx.x * blockDim.x + threadIdx.x) >> 6);
    int lane = threadIdx.x & 63;
    if (wid >= NN) return;
    uint xu = X[(size_t)wid * 64 + lane];
    float2 sc = *(const float2*)&par[2 * lane];
    float2 sh = *(const float2*)&par[128 + 2 * lane];
    float x0 = fmaxf(bflo(xu) * sc.x + sh.x, 0.f);
    float x1 = fmaxf(bfhi(xu) * sc.y + sh.y, 0.f);
    float4 w4 = *(const float4*)&W3[lane * 4];
    float p0 = x0 * w4.x + x1 * w4.z;
    float p1 = x0 * w4.y + x1 * w4.w;
#pragma unroll
    for (int off = 32; off; off >>= 1) {
        p0 += __shfl_xor(p0, off);
        p1 += __shfl_xor(p1, off);
    }
    if (lane == 0) *(float2*)&Z[wid * 2] = make_float2(p0, p1);
}

// ---- layer-3 CSR gather + softmax ----
__global__ void k_l3(const float* __restrict__ Z, const int* __restrict__ rp,
                     const uint2* __restrict__ ec, const float* __restrict__ di,
                     const float* __restrict__ b3, float* __restrict__ out) {
    int n = blockIdx.x * blockDim.x + threadIdx.x;
    if (n >= NN) return;
    int beg = rp[n], end = rp[n + 1];
    float dv = di[n];
    float2 z = *(const float2*)&Z[n * 2];
    float a0 = z.x * dv + b3[0];
    float a1 = z.y * dv + b3[1];
    for (int i = beg; i < end; ++i) {
        uint2 e0 = ec[i];
        float c = __uint_as_float(e0.y);
        float2 v = *(const float2*)&Z[e0.x * 2];
        a0 += v.x * c;
        a1 += v.y * c;
    }
    float m = fmaxf(a0, a1);
    float e0 = __expf(a0 - m), e1 = __expf(a1 - m);
    float inv = 1.0f / (e0 + e1);
    *(float2*)&out[n * 2] = make_float2(e0 * inv, e1 * inv);
}

extern "C" void kernel_launch(void* const* d_in, const int* in_sizes, int n_in,
                              void* d_out, int out_size, void* d_ws, size_t ws_size,
                              hipStream_t stream) {
    const float* x  = (const float*)d_in[0];
    const float* W1 = (const float*)d_in[1];
    const float* b1 = (const float*)d_in[2];
    const float* g1 = (const float*)d_in[3];
    const float* be1= (const float*)d_in[4];
    const float* W2 = (const float*)d_in[5];
    const float* b2 = (const float*)d_in[6];
    const float* g2 = (const float*)d_in[7];
    const float* be2= (const float*)d_in[8];
    const float* W3 = (const float*)d_in[9];
    const float* b3 = (const float*)d_in[10];
    const int*   ei = (const int*)d_in[11];
    const int* srcp = ei;
    const int* dstp = ei + NE;
    float* out = (float*)d_out;

    char* wsp = (char*)d_ws;
    auto alloc = [&](size_t bytes) {
        char* p = wsp;
        wsp += (bytes + 255) & ~(size_t)255;
        return p;
    };
    ushort* Xb   = (ushort*)alloc((size_t)NH * 2);
    ushort* Hb   = (ushort*)alloc((size_t)NH * 2);
    uint*   AGGb = (uint*)alloc((size_t)NN * 64 * 4);
    ushort* Wt   = (ushort*)alloc(16384 * 2);
    float*  Z    = (float*)alloc((size_t)2 * NN * 4);
    float*  dis  = (float*)alloc((size_t)NN * 4);
    float*  di   = (float*)alloc((size_t)NN * 4);
    float*  stats= (float*)alloc(512 * 4);
    float*  par  = (float*)alloc(512 * 4);
    uint2*  ec   = (uint2*)alloc((size_t)NE * 8);
    uint*   ebuf = (uint*)alloc((size_t)NB * CAP * 4);
    int*    gcur = (int*)alloc(NB * 4);
    int*    bstart=(int*)alloc((NB + 1) * 4);
    int*    rp   = (int*)alloc((size_t)(NN + 1) * 4);
    float*  par1 = par;
    float*  par2 = par + 256;

    const int B = 256;
    const int gN  = (NN + B - 1) / B;
    const int gMM = (NN + 127) / 128;
    const int gST = (NN + 63) / 64;
    const int gW  = (int)(((long long)NN * 64 + B - 1) / B);
    const int gCV = (NH / 8 + B - 1) / B;
    const int gPT = (NE + EPB - 1) / EPB;  // 196

    // ---- CSR build (bucketed) ----
    hipMemsetAsync(gcur, 0, NB * sizeof(int), stream);
    k_part<<<gPT, B, 0, stream>>>(srcp, dstp, gcur, ebuf);
    k_bscan<<<1, 256, 0, stream>>>(gcur, bstart, stats, rp);
    k_c1<<<NB, B, 0, stream>>>(ebuf, gcur, bstart, dis, di, rp);
    k_c2<<<NB, B, 0, stream>>>(ebuf, gcur, rp, dis, ec);
    k_cvt_x<<<gCV, B, 0, stream>>>(x, Xb);

    // ---- layer 1 ----
    k_cvt_w<<<64, 256, 0, stream>>>(W1, Wt);
    k_mm_mfma<<<gMM, B, 0, stream>>>(Xb, Wt, nullptr, Hb, NN);
    k_gather_b<<<gW, B, 0, stream>>>(Hb, rp, ec, di, b1, AGGb);
    k_statsb<<<gST, B, 0, stream>>>(AGGb, stats, NN);
    k_bnparams<<<1, 128, 0, stream>>>(stats, g1, be1, par1);

    // ---- layer 2 (BN1+ReLU fused into A-load) ----
    k_cvt_w<<<64, 256, 0, stream>>>(W2, Wt);
    k_mm_mfma<<<gMM, B, 0, stream>>>((const ushort*)AGGb, Wt, par1, Hb, NN);
    k_gather_b<<<gW, B, 0, stream>>>(Hb, rp, ec, di, b2, AGGb);
    k_statsb<<<gST, B, 0, stream>>>(AGGb, stats + 256, NN);
    k_bnparams<<<1, 128, 0, stream>>>(stats + 256, g2, be2, par2);

    // ---- layer 3 (BN2+ReLU fused) + softmax ----
    k_mm2<<<gW, B, 0, stream>>>(AGGb, W3, par2, Z);
    k_l3<<<gN, B, 0, stream>>>(Z, rp, ec, di, b3, out);
}

// Round 6
// 448.933 us; speedup vs baseline: 13.8605x; 1.2436x over previous
//
#include <hip/hip_runtime.h>

#define NN 100000
#define NE 1600000
#define DF 128
#define NH (NN * DF)
#define EPS 1e-5f
#define NB 196        // buckets of 512 dst nodes
#define CAP 10240     // per-bucket edge capacity
#define EPB 8192      // edges per k_part block
#define STB 512       // stats blocks

typedef unsigned int uint;
typedef unsigned short ushort;
typedef __attribute__((ext_vector_type(8))) short bf16x8;
typedef __attribute__((ext_vector_type(4))) float f32x4;

__device__ __forceinline__ ushort f2bf(float f) {
    uint u = __float_as_uint(f);
    u += 0x7fffu + ((u >> 16) & 1u);
    return (ushort)(u >> 16);
}
__device__ __forceinline__ float bflo(uint u) { return __uint_as_float(u << 16); }
__device__ __forceinline__ float bfhi(uint u) { return __uint_as_float(u & 0xffff0000u); }

// ---- pass B: partition edges into 196 bucket lists, packed (src | dloc<<17) ----
__launch_bounds__(256)
__global__ void k_part(const int* __restrict__ src, const int* __restrict__ dst,
                       int* __restrict__ gcur, uint* __restrict__ ebuf) {
    __shared__ int cnt[NB], base[NB];
    int t = threadIdx.x;
    if (t < NB) cnt[t] = 0;
    __syncthreads();
    int e0 = blockIdx.x * EPB;
#pragma unroll
    for (int i = 0; i < EPB / 256; ++i) {
        int e = e0 + i * 256 + t;
        if (e < NE) atomicAdd(&cnt[dst[e] >> 9], 1);
    }
    __syncthreads();
    if (t < NB) {
        base[t] = atomicAdd(&gcur[t], cnt[t]);
        cnt[t] = 0;
    }
    __syncthreads();
#pragma unroll
    for (int i = 0; i < EPB / 256; ++i) {
        int e = e0 + i * 256 + t;
        if (e < NE) {
            int d = dst[e];
            int b = d >> 9;
            int off = atomicAdd(&cnt[b], 1);
            ebuf[b * CAP + base[b] + off] = (uint)src[e] | ((uint)(d & 511) << 17);
        }
    }
}

// ---- scan bucket totals -> bstart; set rp[NN] ----
__global__ void k_bscan(const int* __restrict__ gcur, int* __restrict__ bstart,
                        int* __restrict__ rp) {
    __shared__ int sh[256];
    int t = threadIdx.x;
    int v = (t < NB) ? gcur[t] : 0;
    sh[t] = v;
    __syncthreads();
    for (int off = 1; off < 256; off <<= 1) {
        int x = (t >= off) ? sh[t - off] : 0;
        __syncthreads();
        sh[t] += x;
        __syncthreads();
    }
    if (t < NB) bstart[t] = sh[t] - v;
    if (t == 0) {
        bstart[NB] = NE;
        rp[NN] = NE;
    }
}

// ---- pass C1: per bucket, per-node degree -> dis/di/rp ----
__launch_bounds__(256)
__global__ void k_c1(const uint* __restrict__ ebuf, const int* __restrict__ gcur,
                     const int* __restrict__ bstart, float* __restrict__ dis,
                     float* __restrict__ di, int* __restrict__ rp) {
    __shared__ int ncnt[512];
    __shared__ int ssum[256];
    int b = blockIdx.x, t = threadIdx.x;
    ncnt[t] = 0;
    ncnt[t + 256] = 0;
    __syncthreads();
    int ne = gcur[b];
    const uint* eb = ebuf + (size_t)b * CAP;
    for (int e = t; e < ne; e += 256) atomicAdd(&ncnt[eb[e] >> 17], 1);
    __syncthreads();
    int a0 = ncnt[t * 2], a1 = ncnt[t * 2 + 1];
    int ps = a0 + a1;
    ssum[t] = ps;
    __syncthreads();
    for (int off = 1; off < 256; off <<= 1) {
        int x = (t >= off) ? ssum[t - off] : 0;
        __syncthreads();
        ssum[t] += x;
        __syncthreads();
    }
    int excl = ssum[t] - ps;
    int base = bstart[b];
    int g0 = b * 512 + t * 2;
    if (g0 < NN) {
        rp[g0] = base + excl;
        float d = (float)a0 + 1.0f;
        dis[g0] = rsqrtf(d);
        di[g0] = 1.0f / d;
    }
    if (g0 + 1 < NN) {
        rp[g0 + 1] = base + excl + a0;
        float d = (float)a1 + 1.0f;
        dis[g0 + 1] = rsqrtf(d);
        di[g0 + 1] = 1.0f / d;
    }
}

// ---- pass C2: per bucket, place (src, coef) into CSR window (L2-combined) ----
__launch_bounds__(256)
__global__ void k_c2(const uint* __restrict__ ebuf, const int* __restrict__ gcur,
                     const int* __restrict__ rp, const float* __restrict__ dis,
                     uint2* __restrict__ ec) {
    __shared__ int cur[512];
    __shared__ float dl[512];
    int b = blockIdx.x, t = threadIdx.x;
#pragma unroll
    for (int i = 0; i < 2; ++i) {
        int g = b * 512 + t + i * 256;
        if (g < NN) {
            cur[t + i * 256] = rp[g];
            dl[t + i * 256] = dis[g];
        }
    }
    __syncthreads();
    int ne = gcur[b];
    const uint* eb = ebuf + (size_t)b * CAP;
    for (int e = t; e < ne; e += 256) {
        uint u = eb[e];
        int s = u & 0x1FFFF;
        int dloc = u >> 17;
        int pos = atomicAdd(&cur[dloc], 1);
        ec[pos] = make_uint2((uint)s, __float_as_uint(dis[s] * dl[dloc]));
    }
}

// ---- convert x -> bf16 ----
__global__ void k_cvt_x(const float* __restrict__ X, ushort* __restrict__ Xb) {
    int t = blockIdx.x * blockDim.x + threadIdx.x;
    if (t >= NH / 8) return;
    const float4* X4 = (const float4*)X;
    float4 v0 = X4[t * 2], v1 = X4[t * 2 + 1];
    uint4 o;
    o.x = (uint)f2bf(v0.x) | ((uint)f2bf(v0.y) << 16);
    o.y = (uint)f2bf(v0.z) | ((uint)f2bf(v0.w) << 16);
    o.z = (uint)f2bf(v1.x) | ((uint)f2bf(v1.y) << 16);
    o.w = (uint)f2bf(v1.z) | ((uint)f2bf(v1.w) << 16);
    ((uint4*)Xb)[t] = o;
}

// ---- convert W -> bf16 transposed+swizzled ----
__global__ void k_cvt_w(const float* __restrict__ W, ushort* __restrict__ Wt) {
    int id = blockIdx.x * blockDim.x + threadIdx.x;
    int n = id & 127, k = id >> 7;
    ushort b = f2bf(W[id]);
    int byte = n * 256 + (((k >> 3) ^ (n & 7)) << 4) + ((k & 7) << 1);
    *(ushort*)((char*)Wt + byte) = b;
}

// ---- MFMA matmul, optional fused BN-affine+ReLU on the A operand ----
__launch_bounds__(256, 2)
__global__ void k_mm_mfma(const ushort* __restrict__ Xb, const ushort* __restrict__ Wt,
                          const float* __restrict__ par, ushort* __restrict__ Y,
                          int nrows) {
    __shared__ uint4 ws4[2048];  // 32 KB
    char* ws = (char*)ws4;
    const int tid = threadIdx.x;
    const int wv = tid >> 6, l = tid & 63;
    const int l15 = l & 15, l4 = l >> 4;
    const int row_base = blockIdx.x * 128 + wv * 32;
    const bool act = row_base < nrows;

    bf16x8 a[2][4];
    if (act) {
#pragma unroll
        for (int mt = 0; mt < 2; ++mt)
#pragma unroll
            for (int ks = 0; ks < 4; ++ks) {
                int r = row_base + mt * 16 + l15;
                a[mt][ks] = *(const bf16x8*)&Xb[(size_t)r * 128 + ks * 32 + l4 * 8];
            }
        if (par) {
#pragma unroll
            for (int ks = 0; ks < 4; ++ks) {
                int k0 = ks * 32 + l4 * 8;
                float4 sa = *(const float4*)&par[k0];
                float4 sb = *(const float4*)&par[k0 + 4];
                float4 ha = *(const float4*)&par[128 + k0];
                float4 hb = *(const float4*)&par[128 + k0 + 4];
                float sc[8] = {sa.x, sa.y, sa.z, sa.w, sb.x, sb.y, sb.z, sb.w};
                float sh[8] = {ha.x, ha.y, ha.z, ha.w, hb.x, hb.y, hb.z, hb.w};
#pragma unroll
                for (int mt = 0; mt < 2; ++mt)
#pragma unroll
                    for (int j = 0; j < 8; ++j) {
                        float f = __uint_as_float(((uint)(ushort)a[mt][ks][j]) << 16);
                        f = fmaxf(f * sc[j] + sh[j], 0.0f);
                        a[mt][ks][j] = (short)f2bf(f);
                    }
            }
        }
    }
    const uint4* Wg = (const uint4*)Wt;
#pragma unroll
    for (int i = 0; i < 8; ++i) ws4[tid + i * 256] = Wg[tid + i * 256];
    __syncthreads();
    if (!act) return;

    f32x4 acc[2][8];
#pragma unroll
    for (int mt = 0; mt < 2; ++mt)
#pragma unroll
        for (int nt = 0; nt < 8; ++nt) acc[mt][nt] = (f32x4){0.f, 0.f, 0.f, 0.f};

#pragma unroll
    for (int ks = 0; ks < 4; ++ks) {
        bf16x8 b[8];
#pragma unroll
        for (int nt = 0; nt < 8; ++nt) {
            int n = nt * 16 + l15;
            int chunk = (ks * 4 + l4) ^ (n & 7);
            b[nt] = *(const bf16x8*)(ws + n * 256 + chunk * 16);
        }
#pragma unroll
        for (int nt = 0; nt < 8; ++nt) {
            acc[0][nt] = __builtin_amdgcn_mfma_f32_16x16x32_bf16(a[0][ks], b[nt], acc[0][nt], 0, 0, 0);
            acc[1][nt] = __builtin_amdgcn_mfma_f32_16x16x32_bf16(a[1][ks], b[nt], acc[1][nt], 0, 0, 0);
        }
    }
#pragma unroll
    for (int mt = 0; mt < 2; ++mt)
#pragma unroll
        for (int nt = 0; nt < 8; ++nt)
#pragma unroll
            for (int r = 0; r < 4; ++r) {
                int ro = row_base + mt * 16 + l4 * 4 + r;
                Y[(size_t)ro * 128 + nt * 16 + l15] = f2bf(acc[mt][nt][r]);
            }
}

// ---- CSR gather (bf16 H) -> bf16 agg; one wave/node, 4-deep unroll ----
__launch_bounds__(256)
__global__ void k_gather_b(const ushort* __restrict__ H, const int* __restrict__ rp,
                           const uint2* __restrict__ ec, const float* __restrict__ di,
                           const float* __restrict__ b, uint* __restrict__ outb) {
    int wid = (int)(((long long)blockIdx.x * blockDim.x + threadIdx.x) >> 6);
    int lane = threadIdx.x & 63;
    if (wid >= NN) return;
    int beg = rp[wid], end = rp[wid + 1];
    float dv = di[wid];
    const uint* H32 = (const uint*)H;
    uint hu = H32[(size_t)wid * 64 + lane];
    float2 bb = *(const float2*)&b[lane * 2];
    float ax = bflo(hu) * dv + bb.x;
    float ay = bfhi(hu) * dv + bb.y;
    int i = beg;
    for (; i + 3 < end; i += 4) {
        uint2 e0 = ec[i], e1 = ec[i + 1], e2 = ec[i + 2], e3 = ec[i + 3];
        uint u0 = H32[(size_t)e0.x * 64 + lane];
        uint u1 = H32[(size_t)e1.x * 64 + lane];
        uint u2 = H32[(size_t)e2.x * 64 + lane];
        uint u3 = H32[(size_t)e3.x * 64 + lane];
        float c0 = __uint_as_float(e0.y), c1 = __uint_as_float(e1.y);
        float c2 = __uint_as_float(e2.y), c3 = __uint_as_float(e3.y);
        ax += bflo(u0) * c0 + bflo(u1) * c1 + bflo(u2) * c2 + bflo(u3) * c3;
        ay += bfhi(u0) * c0 + bfhi(u1) * c1 + bfhi(u2) * c2 + bfhi(u3) * c3;
    }
    for (; i < end; ++i) {
        uint2 e0 = ec[i];
        uint u = H32[(size_t)e0.x * 64 + lane];
        float c = __uint_as_float(e0.y);
        ax += bflo(u) * c;
        ay += bfhi(u) * c;
    }
    outb[(size_t)wid * 64 + lane] = (uint)f2bf(ax) | ((uint)f2bf(ay) << 16);
}

// ---- column stats over bf16 agg: grid-stride, NO atomics, per-block partials ----
__launch_bounds__(256)
__global__ void k_statsb(const uint* __restrict__ V, float* __restrict__ partial,
                         int nrows) {
    int cp = threadIdx.x & 63;
    int q = threadIdx.x >> 6;
    float s0 = 0.f, s1 = 0.f, q0 = 0.f, q1 = 0.f;
    for (int r = blockIdx.x * 4 + q; r < nrows; r += STB * 4) {
        uint u = V[(size_t)r * 64 + cp];
        float lo = bflo(u), hi = bfhi(u);
        s0 += lo;
        q0 += lo * lo;
        s1 += hi;
        q1 += hi * hi;
    }
    __shared__ float L[4][256];
    L[0][threadIdx.x] = s0;
    L[1][threadIdx.x] = s1;
    L[2][threadIdx.x] = q0;
    L[3][threadIdx.x] = q1;
    __syncthreads();
    if (q == 0) {
        float a = 0.f, b = 0.f, c = 0.f, d = 0.f;
#pragma unroll
        for (int j = 0; j < 4; ++j) {
            a += L[0][cp + j * 64];
            b += L[1][cp + j * 64];
            c += L[2][cp + j * 64];
            d += L[3][cp + j * 64];
        }
        float* P = partial + (size_t)blockIdx.x * 256;
        P[2 * cp] = a;
        P[2 * cp + 1] = b;
        P[128 + 2 * cp] = c;
        P[128 + 2 * cp + 1] = d;
    }
}

// ---- reduce partials + BN params (fused) ----
__global__ void k_red(const float* __restrict__ partial, const float* __restrict__ g,
                      const float* __restrict__ be, float* __restrict__ par) {
    int c = threadIdx.x;  // 0..255
    float acc = 0.f;
    for (int b = 0; b < STB; ++b) acc += partial[b * 256 + c];
    __shared__ float sh[256];
    sh[c] = acc;
    __syncthreads();
    if (c < 128) {
        float mu = sh[c] * (1.0f / NN);
        float var = sh[c + 128] * (1.0f / NN) - mu * mu;
        float inv = rsqrtf(var + EPS);
        float scv = inv * g[c];
        par[c] = scv;
        par[128 + c] = be[c] - mu * scv;
    }
}

// ---- layer-3: affine+relu on bf16 agg, dot W3; one wave per node ----
__global__ void k_mm2(const uint* __restrict__ X, const float* __restrict__ W3,
                      const float* __restrict__ par, float* __restrict__ Z) {
    int wid = (int)(((long long)blockIdx.x * blockDim.x + threadIdx.x) >> 6);
    int lane = threadIdx.x & 63;
    if (wid >= NN) return;
    uint xu = X[(size_t)wid * 64 + lane];
    float2 sc = *(const float2*)&par[2 * lane];
    float2 sh = *(const float2*)&par[128 + 2 * lane];
    float x0 = fmaxf(bflo(xu) * sc.x + sh.x, 0.f);
    float x1 = fmaxf(bfhi(xu) * sc.y + sh.y, 0.f);
    float4 w4 = *(const float4*)&W3[lane * 4];
    float p0 = x0 * w4.x + x1 * w4.z;
    float p1 = x0 * w4.y + x1 * w4.w;
#pragma unroll
    for (int off = 32; off; off >>= 1) {
        p0 += __shfl_xor(p0, off);
        p1 += __shfl_xor(p1, off);
    }
    if (lane == 0) *(float2*)&Z[wid * 2] = make_float2(p0, p1);
}

// ---- layer-3 CSR gather + softmax ----
__global__ void k_l3(const float* __restrict__ Z, const int* __restrict__ rp,
                     const uint2* __restrict__ ec, const float* __restrict__ di,
                     const float* __restrict__ b3, float* __restrict__ out) {
    int n = blockIdx.x * blockDim.x + threadIdx.x;
    if (n >= NN) return;
    int beg = rp[n], end = rp[n + 1];
    float dv = di[n];
    float2 z = *(const float2*)&Z[n * 2];
    float a0 = z.x * dv + b3[0];
    float a1 = z.y * dv + b3[1];
    for (int i = beg; i < end; ++i) {
        uint2 e0 = ec[i];
        float c = __uint_as_float(e0.y);
        float2 v = *(const float2*)&Z[e0.x * 2];
        a0 += v.x * c;
        a1 += v.y * c;
    }
    float m = fmaxf(a0, a1);
    float e0 = __expf(a0 - m), e1 = __expf(a1 - m);
    float inv = 1.0f / (e0 + e1);
    *(float2*)&out[n * 2] = make_float2(e0 * inv, e1 * inv);
}

extern "C" void kernel_launch(void* const* d_in, const int* in_sizes, int n_in,
                              void* d_out, int out_size, void* d_ws, size_t ws_size,
                              hipStream_t stream) {
    const float* x  = (const float*)d_in[0];
    const float* W1 = (const float*)d_in[1];
    const float* b1 = (const float*)d_in[2];
    const float* g1 = (const float*)d_in[3];
    const float* be1= (const float*)d_in[4];
    const float* W2 = (const float*)d_in[5];
    const float* b2 = (const float*)d_in[6];
    const float* g2 = (const float*)d_in[7];
    const float* be2= (const float*)d_in[8];
    const float* W3 = (const float*)d_in[9];
    const float* b3 = (const float*)d_in[10];
    const int*   ei = (const int*)d_in[11];
    const int* srcp = ei;
    const int* dstp = ei + NE;
    float* out = (float*)d_out;

    char* wsp = (char*)d_ws;
    auto alloc = [&](size_t bytes) {
        char* p = wsp;
        wsp += (bytes + 255) & ~(size_t)255;
        return p;
    };
    ushort* Xb   = (ushort*)alloc((size_t)NH * 2);
    ushort* Hb   = (ushort*)alloc((size_t)NH * 2);
    uint*   AGGb = (uint*)alloc((size_t)NN * 64 * 4);
    ushort* Wt   = (ushort*)alloc(16384 * 2);
    float*  Z    = (float*)alloc((size_t)2 * NN * 4);
    float*  dis  = (float*)alloc((size_t)NN * 4);
    float*  di   = (float*)alloc((size_t)NN * 4);
    float*  partial = (float*)alloc((size_t)STB * 256 * 4);
    float*  par  = (float*)alloc(512 * 4);
    uint2*  ec   = (uint2*)alloc((size_t)NE * 8);
    uint*   ebuf = (uint*)alloc((size_t)NB * CAP * 4);
    int*    gcur = (int*)alloc(NB * 4);
    int*    bstart=(int*)alloc((NB + 1) * 4);
    int*    rp   = (int*)alloc((size_t)(NN + 1) * 4);
    float*  par1 = par;
    float*  par2 = par + 256;

    const int B = 256;
    const int gN  = (NN + B - 1) / B;
    const int gMM = (NN + 127) / 128;
    const int gW  = (int)(((long long)NN * 64 + B - 1) / B);
    const int gCV = (NH / 8 + B - 1) / B;
    const int gPT = (NE + EPB - 1) / EPB;  // 196

    // ---- CSR build (bucketed) ----
    hipMemsetAsync(gcur, 0, NB * sizeof(int), stream);
    k_part<<<gPT, B, 0, stream>>>(srcp, dstp, gcur, ebuf);
    k_bscan<<<1, 256, 0, stream>>>(gcur, bstart, rp);
    k_c1<<<NB, B, 0, stream>>>(ebuf, gcur, bstart, dis, di, rp);
    k_c2<<<NB, B, 0, stream>>>(ebuf, gcur, rp, dis, ec);
    k_cvt_x<<<gCV, B, 0, stream>>>(x, Xb);

    // ---- layer 1 ----
    k_cvt_w<<<64, 256, 0, stream>>>(W1, Wt);
    k_mm_mfma<<<gMM, B, 0, stream>>>(Xb, Wt, nullptr, Hb, NN);
    k_gather_b<<<gW, B, 0, stream>>>(Hb, rp, ec, di, b1, AGGb);
    k_statsb<<<STB, B, 0, stream>>>(AGGb, partial, NN);
    k_red<<<1, 256, 0, stream>>>(partial, g1, be1, par1);

    // ---- layer 2 (BN1+ReLU fused into A-load) ----
    k_cvt_w<<<64, 256, 0, stream>>>(W2, Wt);
    k_mm_mfma<<<gMM, B, 0, stream>>>((const ushort*)AGGb, Wt, par1, Hb, NN);
    k_gather_b<<<gW, B, 0, stream>>>(Hb, rp, ec, di, b2, AGGb);
    k_statsb<<<STB, B, 0, stream>>>(AGGb, partial, NN);
    k_red<<<1, 256, 0, stream>>>(partial, g2, be2, par2);

    // ---- layer 3 (BN2+ReLU fused) + softmax ----
    k_mm2<<<gW, B, 0, stream>>>(AGGb, W3, par2, Z);
    k_l3<<<gN, B, 0, stream>>>(Z, rp, ec, di, b3, out);
}